// Round 10
// baseline (2060.766 us; speedup 1.0000x reference)
//
#include <hip/hip_runtime.h>
#include <hip/hip_bf16.h>

typedef __hip_bfloat16 bf16;
typedef unsigned short u16;
typedef unsigned int u32;

#define DIM 64
#define BN_EPS 1e-5f

struct ParamPack {
    const void* p[18];
    int n[18];
    int off[18];
};

// ---- read element i of p as float, interpreting per flag (1=bf16, 0=f32) ----
__device__ __forceinline__ float load_as(const void* p, int i, int isbf16) {
    if (isbf16) {
        unsigned short b = ((const unsigned short*)p)[i];
        unsigned int u = ((unsigned int)b) << 16;
        return __uint_as_float(u);
    }
    return ((const float*)p)[i];
}

__device__ __forceinline__ float bf2f(unsigned short b) {
    unsigned int u = ((unsigned int)b) << 16;
    return __uint_as_float(u);
}

// round-to-nearest-even f32 -> bf16 bits (finite values only)
__device__ __forceinline__ unsigned short f2bf(float f) {
    unsigned int u = __float_as_uint(f);
    unsigned int r = u + 0x7fff + ((u >> 16) & 1);
    return (unsigned short)(r >> 16);
}

// ---- dtype detect: scan w1a (values uniform in +-0.125). bf16 interp of real
// bf16 data passes ~100%; bf16 interp of f32 bits passes ~55%. ----
__global__ void gin_detect(const void* w, int nelem, int* flag) {
    const unsigned short* u = (const unsigned short*)w;
    int tid = threadIdx.x;
    int cnt = 0;
    for (int i = tid; i < nelem; i += blockDim.x) {
        unsigned int f = ((unsigned int)u[i]) << 16;
        float v = __uint_as_float(f);
        float av = fabsf(v);
        if (av <= 0.126f && (av == 0.0f || av >= 1e-8f)) cnt++;
    }
    __shared__ int sc[256];
    sc[tid] = cnt;
    __syncthreads();
    for (int s = 128; s > 0; s >>= 1) {
        if (tid < s) sc[tid] += sc[tid + s];
        __syncthreads();
    }
    if (tid == 0) flag[0] = (sc[0] * 10 >= nelem * 9) ? 1 : 0;
}

// ---- stage all 18 param tensors into f32 workspace ----
__global__ void gin_cvt_params(ParamPack pk, float* __restrict__ out,
                               const int* __restrict__ flag) {
    int b = blockIdx.x;
    int f = flag[0];
    const void* p = pk.p[b];
    float* o = out + pk.off[b];
    int n = pk.n[b];
    for (int i = threadIdx.x; i < n; i += blockDim.x) o[i] = load_as(p, i, f);
}

// ---- x -> bf16 h, vectorized 4/thread (named with problem identifier) ----
__global__ void GINEncoder_16114717295311_kernel(const void* __restrict__ x,
                                                 u16* __restrict__ h, int n4,
                                                 const int* __restrict__ flag) {
    int i = blockIdx.x * blockDim.x + threadIdx.x;   // group-of-4 index
    int f = flag[0];
    if (i < n4) {
        ushort4 o;
        if (f) {
            o = ((const ushort4*)x)[i];
        } else {
            float4 v = ((const float4*)x)[i];
            o.x = f2bf(v.x); o.y = f2bf(v.y); o.z = f2bf(v.z); o.w = f2bf(v.w);
        }
        ((ushort4*)h)[i] = o;
    }
}

__global__ void gin_zero(float* __restrict__ p, int n) {
    int i = blockIdx.x * blockDim.x + threadIdx.x;
    if (i < n) p[i] = 0.0f;
}

// ======================= edge bucketing (once; reused 3x) =======================
// History: r3 random fill = 17x write amp; r5 direct global atomics = 431 us
// contention; r7 LDS-privatized 3-phase chain = fast. r10: bucket size = TILE
// size (64 rows, shift=6) and the per-row CSR (bfill/rowptr/adj) is DELETED --
// the fused kernel consumes bucket-grouped edges flat, accumulating in LDS.

// bucket-count histogram, LDS-privatized (one flush atomic per block+bucket)
__global__ void gin_bhist(const int* __restrict__ dst, int* __restrict__ bcnt,
                          int E, int shift, int nbuck) {
    __shared__ int lh[2048];
    int tid = threadIdx.x;
    for (int i = tid; i < nbuck; i += 256) lh[i] = 0;
    __syncthreads();
    int stride = gridDim.x * 256;
    for (int e = blockIdx.x * 256 + tid; e < E; e += stride)
        atomicAdd(&lh[dst[e] >> shift], 1);
    __syncthreads();
    for (int i = tid; i < nbuck; i += 256) {
        int c = lh[i];
        if (c) atomicAdd(&bcnt[i], c);
    }
}

// single block, exclusive scan over up to 2048 ints (in place)
__global__ void gin_scan2(int* __restrict__ part, int NB) {
    __shared__ int lds[256];
    int tid = threadIdx.x;
    int base = tid * 8;
    int a[8];
    int s = 0;
    #pragma unroll
    for (int k = 0; k < 8; k++) {
        a[k] = (base + k < NB) ? part[base + k] : 0;
        s += a[k];
    }
    lds[tid] = s;
    __syncthreads();
    for (int off = 1; off < 256; off <<= 1) {
        int v = (tid >= off) ? lds[tid - off] : 0;
        __syncthreads();
        lds[tid] += v;
        __syncthreads();
    }
    int p = lds[tid] - s;  // exclusive prefix
    #pragma unroll
    for (int k = 0; k < 8; k++) {
        if (base + k < NB) { part[base + k] = p; p += a[k]; }
    }
}

// block-local multi-split scatter: each block takes MS_CHUNK contiguous edges,
// computes per-bucket local positions in LDS, reserves bucket space with ONE
// global atomic per (block,bucket), then writes (src,dst) bucket-grouped.
#define MS_CHUNK 12288
__global__ void gin_mscatter(const int* __restrict__ src, const int* __restrict__ dst,
                             const int* __restrict__ bbase, int* __restrict__ bcur,
                             int2* __restrict__ ebuf, int E, int shift, int nbuck) {
    __shared__ unsigned short spos[MS_CHUNK];  // 24 KB
    __shared__ int lcnt[2048];                 // 8 KB
    __shared__ int lbase[2048];                // 8 KB
    int tid = threadIdx.x;  // 512
    int e0 = blockIdx.x * MS_CHUNK;
    int ecnt = min(MS_CHUNK, E - e0);
    for (int i = tid; i < nbuck; i += 512) lcnt[i] = 0;
    __syncthreads();
    for (int i = tid; i < ecnt; i += 512) {
        int b = dst[e0 + i] >> shift;
        spos[i] = (unsigned short)atomicAdd(&lcnt[b], 1);
    }
    __syncthreads();
    for (int i = tid; i < nbuck; i += 512) {
        int c = lcnt[i];
        lbase[i] = c ? (bbase[i] + atomicAdd(&bcur[i], c)) : 0;
    }
    __syncthreads();
    for (int i = tid; i < ecnt; i += 512) {
        int d = dst[e0 + i];
        int b = d >> shift;
        ebuf[lbase[b] + spos[i]] = make_int2(src[e0 + i], d);
    }
}

// ======================= per-layer fused kernel =======================

// Fused gather + MLP, v5 (flat-edge gather). r9's row-serial gather was
// dependency-chain bound: per row-pair, adj-load -> 8 dependent h-loads ->
// sum, with DATA-DEPENDENT divergent trip counts -> compiler can't pipeline;
// 114 us at VALU 27% / HBM 20% / occ 46% (all low = latency). v5 streams the
// block's contiguous bucket-grouped edge slice with UNIFORM bounds:
//   init sT with self rows (coalesced) ->
//   per wave-instr: 2 edges x 64 ch: broadcast int2 -> uint h-load/lane ->
//   2 LDS f32 atomicAdds (+deg count) ->
//   tile-wide BN affine scale*acc + (1+deg)*shift (ss computed in-block from
//   prev-layer stats; identity for layer 1) -> GEMM pair as before.
// Grid = NBUCK (bucket b == 64-row tile b). 512 thr / 8 waves, LDS ~38.9 KB.
__global__ void gin_gmlp(const u16* __restrict__ hin, void* __restrict__ hout,
                         const int2* __restrict__ ebuf, const int* __restrict__ bbase,
                         const float* __restrict__ pstats, const float* __restrict__ pgamma,
                         const float* __restrict__ pbeta,
                         const float* __restrict__ Wa, const float* __restrict__ Ba,
                         const float* __restrict__ Wb, const float* __restrict__ Bb,
                         float* __restrict__ stats, int N, int E, float invN, int outf32) {
    __shared__ float sW[DIM * DIM];     // 16 KB, Wa then Wb
    __shared__ float sT[64][DIM + 4];   // 17 KB; +4 pad keeps rows 16B-aligned
    __shared__ float sBa[DIM], sBb[DIM], sSS[2 * DIM];
    __shared__ float sred[8][16][8];    // 4 KB
    __shared__ int sDeg[64];

    int tid = threadIdx.x;              // 512
    int lane = tid & 63, wave = tid >> 6;
    int b = blockIdx.x;
    int rbase = b * 64;

    for (int i = tid; i < DIM * DIM; i += 512) sW[i] = Wa[i];
    if (tid < DIM) { sBa[tid] = Ba[tid]; sBb[tid] = Bb[tid]; sDeg[tid] = 0; }
    if (tid >= 64 && tid < 128) {
        int d = tid - 64;
        float sc = 1.f, sh = 0.f;
        if (pstats) {
            float m = pstats[d] * invN;
            float var = pstats[DIM + d] * invN - m * m;
            sc = pgamma[d] * rsqrtf(var + BN_EPS);
            sh = pbeta[d] - sc * m;
        }
        sSS[d] = sc; sSS[DIM + d] = sh;
    }
    // init sT with self rows (64 rows x 32 uint-cols, coalesced)
    for (int i = tid; i < 2048; i += 512) {
        int rr = i >> 5, c = i & 31;
        int row = rbase + rr;
        float2 v = make_float2(0.f, 0.f);
        if (row < N) {
            u32 u = *(const u32*)&hin[(size_t)row * DIM + 2 * c];
            v.x = bf2f((u16)u); v.y = bf2f((u16)(u >> 16));
        }
        *(float2*)&sT[rr][2 * c] = v;
    }
    __syncthreads();

    // ---- flat edge accumulation over this block's contiguous ebuf slice ----
    {
        int eb = bbase[b];
        int ee = (b + 1 < gridDim.x) ? bbase[b + 1] : E;
        int nE = ee - eb;
        int half = lane >> 5, c = lane & 31;
        for (int base2 = wave * 16; base2 < nE; base2 += 128) {
            #pragma unroll
            for (int k = 0; k < 8; k++) {
                int e = base2 + 2 * k + half;
                if (e < nE) {
                    int2 sd = ebuf[eb + e];
                    u32 u = *(const u32*)&hin[(size_t)sd.x * DIM + 2 * c];
                    int lr = sd.y - rbase;
                    atomicAdd(&sT[lr][2 * c],     bf2f((u16)u));
                    atomicAdd(&sT[lr][2 * c + 1], bf2f((u16)(u >> 16)));
                    if (c == 0) atomicAdd(&sDeg[lr], 1);
                }
            }
        }
    }
    __syncthreads();

    // ---- BN affine of previous layer: scale*acc + (1+deg)*shift ----
    for (int i = tid; i < 64 * DIM; i += 512) {
        int rr = i >> 6, ch = i & 63;
        float v = 0.f;
        if (rbase + rr < N)
            v = sSS[ch] * sT[rr][ch] + (float)(1 + sDeg[rr]) * sSS[DIM + ch];
        sT[rr][ch] = v;
    }
    __syncthreads();

    // ---- GEMM pair, each thread owns rows r0..r0+1 x cols c0..c0+3 ----
    int tx = tid & 15, ty = tid >> 4;   // ty 0..31
    int c0 = tx * 4;
    int r0 = ty * 2;
    float acc[2][4];

    // GEMM1: mid = relu(tile @ Wa + Ba)
    {
        float4 bia = *(const float4*)&sBa[c0];
        #pragma unroll
        for (int i = 0; i < 2; i++) {
            acc[i][0] = bia.x; acc[i][1] = bia.y; acc[i][2] = bia.z; acc[i][3] = bia.w;
        }
    }
    #pragma unroll 8
    for (int k = 0; k < DIM; k++) {
        float4 bb4 = *(const float4*)&sW[k * DIM + c0];
        float a0 = sT[r0 + 0][k], a1 = sT[r0 + 1][k];
        acc[0][0] = fmaf(a0, bb4.x, acc[0][0]); acc[0][1] = fmaf(a0, bb4.y, acc[0][1]);
        acc[0][2] = fmaf(a0, bb4.z, acc[0][2]); acc[0][3] = fmaf(a0, bb4.w, acc[0][3]);
        acc[1][0] = fmaf(a1, bb4.x, acc[1][0]); acc[1][1] = fmaf(a1, bb4.y, acc[1][1]);
        acc[1][2] = fmaf(a1, bb4.z, acc[1][2]); acc[1][3] = fmaf(a1, bb4.w, acc[1][3]);
    }
    __syncthreads();  // all GEMM1 reads of sT and sW done

    // mid -> sT; reload sW = Wb (overlaps)
    #pragma unroll
    for (int i = 0; i < 2; i++) {
        float4 m;
        m.x = fmaxf(acc[i][0], 0.f); m.y = fmaxf(acc[i][1], 0.f);
        m.z = fmaxf(acc[i][2], 0.f); m.w = fmaxf(acc[i][3], 0.f);
        *(float4*)&sT[r0 + i][c0] = m;
    }
    for (int i = tid; i < DIM * DIM; i += 512) sW[i] = Wb[i];
    __syncthreads();

    // GEMM2: out = relu(mid @ Wb + Bb)
    {
        float4 bib = *(const float4*)&sBb[c0];
        #pragma unroll
        for (int i = 0; i < 2; i++) {
            acc[i][0] = bib.x; acc[i][1] = bib.y; acc[i][2] = bib.z; acc[i][3] = bib.w;
        }
    }
    #pragma unroll 8
    for (int k = 0; k < DIM; k++) {
        float4 bb4 = *(const float4*)&sW[k * DIM + c0];
        float a0 = sT[r0 + 0][k], a1 = sT[r0 + 1][k];
        acc[0][0] = fmaf(a0, bb4.x, acc[0][0]); acc[0][1] = fmaf(a0, bb4.y, acc[0][1]);
        acc[0][2] = fmaf(a0, bb4.z, acc[0][2]); acc[0][3] = fmaf(a0, bb4.w, acc[0][3]);
        acc[1][0] = fmaf(a1, bb4.x, acc[1][0]); acc[1][1] = fmaf(a1, bb4.y, acc[1][1]);
        acc[1][2] = fmaf(a1, bb4.z, acc[1][2]); acc[1][3] = fmaf(a1, bb4.w, acc[1][3]);
    }

    // relu, store (bf16 or f32), per-thread BN partials (valid rows only)
    float s[4] = {0.f, 0.f, 0.f, 0.f}, q[4] = {0.f, 0.f, 0.f, 0.f};
    #pragma unroll
    for (int i = 0; i < 2; i++) {
        int r = rbase + r0 + i;
        float4 o;
        o.x = fmaxf(acc[i][0], 0.f); o.y = fmaxf(acc[i][1], 0.f);
        o.z = fmaxf(acc[i][2], 0.f); o.w = fmaxf(acc[i][3], 0.f);
        if (r < N) {
            if (outf32) {
                *(float4*)&((float*)hout)[(size_t)r * DIM + c0] = o;
            } else {
                ushort4 ub;
                ub.x = f2bf(o.x); ub.y = f2bf(o.y); ub.z = f2bf(o.z); ub.w = f2bf(o.w);
                *(ushort4*)&((u16*)hout)[(size_t)r * DIM + c0] = ub;
            }
            s[0] += o.x; q[0] += o.x * o.x;
            s[1] += o.y; q[1] += o.y * o.y;
            s[2] += o.z; q[2] += o.z * o.z;
            s[3] += o.w; q[3] += o.w * o.w;
        }
    }
    // reduce over the row-groups within each wave: lanes +16, +32
    #pragma unroll
    for (int j = 0; j < 4; j++) {
        s[j] += __shfl_xor(s[j], 16); s[j] += __shfl_xor(s[j], 32);
        q[j] += __shfl_xor(q[j], 16); q[j] += __shfl_xor(q[j], 32);
    }
    if (lane < 16) {
        #pragma unroll
        for (int j = 0; j < 4; j++) {
            sred[wave][lane][j] = s[j];
            sred[wave][lane][4 + j] = q[j];
        }
    }
    __syncthreads();
    if (tid < DIM) {
        int txx = tid >> 2, j = tid & 3;
        float as = 0.f, aq = 0.f;
        #pragma unroll
        for (int w = 0; w < 8; w++) {
            as += sred[w][txx][j];
            aq += sred[w][txx][4 + j];
        }
        atomicAdd(&stats[tid], as);
        atomicAdd(&stats[DIM + tid], aq);
    }
}

// pool with folded BN3 (affine computed inline from stats3): one wave per graph
// (batch sorted -> binary search range), direct write to d_out. No atomics.
__global__ void gin_pool(const float* __restrict__ h, const int* __restrict__ batch,
                         const float* __restrict__ stats, const float* __restrict__ gamma,
                         const float* __restrict__ beta, float invN,
                         void* __restrict__ out, int N, int G,
                         const int* __restrict__ flag) {
    int gw = (blockIdx.x * blockDim.x + threadIdx.x) >> 6;
    int lane = threadIdx.x & 63;
    if (gw >= G) return;
    float m = stats[lane] * invN;
    float var = stats[DIM + lane] * invN - m * m;
    float sc = gamma[lane] * rsqrtf(var + BN_EPS);
    float sh = beta[lane] - sc * m;
    int lo = 0, hi = N;
    while (lo < hi) { int mid = (lo + hi) >> 1; if (batch[mid] < gw) lo = mid + 1; else hi = mid; }
    int s0 = lo;
    hi = N;
    while (lo < hi) { int mid = (lo + hi) >> 1; if (batch[mid] < gw + 1) lo = mid + 1; else hi = mid; }
    int s1 = lo;
    float a0 = 0.f, a1 = 0.f, a2 = 0.f, a3 = 0.f;
    int n = s0;
    for (; n + 3 < s1; n += 4) {
        a0 += h[n * DIM + lane];
        a1 += h[(n + 1) * DIM + lane];
        a2 += h[(n + 2) * DIM + lane];
        a3 += h[(n + 3) * DIM + lane];
    }
    for (; n < s1; n++) a0 += h[n * DIM + lane];
    float acc = (a0 + a1) + (a2 + a3);
    float v = sc * acc + (float)(s1 - s0) * sh;
    int f = flag[0];
    if (f) ((bf16*)out)[gw * DIM + lane] = __float2bfloat16(v);
    else   ((float*)out)[gw * DIM + lane] = v;
}

extern "C" void kernel_launch(void* const* d_in, const int* in_sizes, int n_in,
                              void* d_out, int out_size, void* d_ws, size_t ws_size,
                              hipStream_t stream) {
    (void)hipGetLastError();  // clear any stale error

    const int N = in_sizes[0] / DIM;   // F_IN == DIM == 64
    const int E = in_sizes[1] / 2;
    const int G = out_size / DIM;
    const size_t ND = (size_t)N * DIM;

    const void* x     = d_in[0];
    const int*  ei    = (const int*)d_in[1];
    const int*  srcp  = ei;
    const int*  dstp  = ei + E;
    const int*  batch = (const int*)d_in[2];

    // bucket = 64-row tile (shift 6); NBUCK must fit the 2048-wide scan/LDS
    const int SHIFT = 6;
    const int NBUCK = ((N - 1) >> SHIFT) + 1;   // N=100k -> 1563 <= 2048

    // workspace layout (no aliasing; ebuf persists across layers)
    int*   flag  = (int*)d_ws;
    float* P     = (float*)d_ws + 64;          // staged f32 params (25344 used)
    float* stats = P + 25600;                  // [384] = 3 layers x 128
    u16*   hA    = (u16*)(stats + 384 + 32);   // [ND] bf16 (16B aligned)
    u16*   hB    = hA + ND;                    // [ND] bf16
    float* F     = (float*)(hA + 2 * ND);      // [ND] f32 (layer-3 out)
    int2*  ebuf  = (int2*)(F + ND);            // [E] bucket-grouped (src,dst)
    int*   bcnt  = (int*)(ebuf + E);           // [2048] counts -> bases
    int*   bcur  = bcnt + 2048;                // [2048] reservation cursors
    size_t need  = (char*)(bcur + 2048) - (char*)d_ws;
    if (ws_size < need || NBUCK > 2048) {  // marker: err prints ~5e33
        hipMemsetAsync(d_out, 0x77, (size_t)out_size * 2, stream);
        return;
    }

    // param staging pack: per layer {wa, ba, wb, bb, gamma, beta}
    ParamPack pk;
    int off = 0;
    for (int l = 0; l < 3; l++) {
        for (int j = 0; j < 6; j++) {
            int idx = 3 + 6 * l + j;
            pk.p[6 * l + j]   = d_in[idx];
            pk.n[6 * l + j]   = in_sizes[idx];
            pk.off[6 * l + j] = off;
            off += in_sizes[idx];
        }
    }
    float* wa[3], *ba[3], *wb[3], *bb[3], *gm[3], *be[3];
    for (int l = 0; l < 3; l++) {
        float* base = P + l * 8448;
        wa[l] = base;        ba[l] = base + 4096;
        wb[l] = base + 4160; bb[l] = base + 8256;
        gm[l] = base + 8320; be[l] = base + 8384;
    }

    const int TB = 256;
    const int grid_nd4 = (int)((ND / 4 + TB - 1) / TB);
    const int grid_g   = (G * DIM + TB - 1) / TB;
    const int grid_ms  = (E + MS_CHUNK - 1) / MS_CHUNK;
    const float invN   = 1.0f / (float)N;

    gin_detect<<<1, 256, 0, stream>>>(d_in[3], in_sizes[3], flag);
    gin_cvt_params<<<18, 256, 0, stream>>>(pk, P, flag);
    GINEncoder_16114717295311_kernel<<<grid_nd4, TB, 0, stream>>>(x, hA, (int)(ND / 4), flag);

    // ---- edge bucketing (once; reused by all 3 layers) ----
    gin_zero<<<16, TB, 0, stream>>>((float*)bcnt, 4096);              // bcnt + bcur
    gin_bhist<<<256, 256, 0, stream>>>(dstp, bcnt, E, SHIFT, NBUCK);
    gin_scan2<<<1, 256, 0, stream>>>(bcnt, NBUCK);                    // -> exclusive bases
    gin_mscatter<<<grid_ms, 512, 0, stream>>>(srcp, dstp, bcnt, bcur, ebuf, E, SHIFT, NBUCK);

    gin_zero<<<2, TB, 0, stream>>>(stats, 384);

    // L1: hA -> hB (identity affine), L2: hB -> hA, L3: hA -> F (f32)
    gin_gmlp<<<NBUCK, 512, 0, stream>>>(hA, hB, ebuf, bcnt,
                                        nullptr, nullptr, nullptr,
                                        wa[0], ba[0], wb[0], bb[0],
                                        stats + 0, N, E, invN, 0);
    gin_gmlp<<<NBUCK, 512, 0, stream>>>(hB, hA, ebuf, bcnt,
                                        stats + 0, gm[0], be[0],
                                        wa[1], ba[1], wb[1], bb[1],
                                        stats + 128, N, E, invN, 0);
    gin_gmlp<<<NBUCK, 512, 0, stream>>>(hA, F, ebuf, bcnt,
                                        stats + 128, gm[1], be[1],
                                        wa[2], ba[2], wb[2], bb[2],
                                        stats + 256, N, E, invN, 1);

    gin_pool<<<grid_g, TB, 0, stream>>>(F, batch, stats + 256, gm[2], be[2], invN,
                                        d_out, N, G, flag);

    // "some launch failed" marker: err prints ~1.7e38 (bf16) / 3.4e38 (f32)
    hipError_t e = hipGetLastError();
    if (e != hipSuccess) {
        hipMemsetAsync(d_out, 0x7F, (size_t)out_size * 2, stream);
    }
}

// Round 11
// 536.594 us; speedup vs baseline: 3.8405x; 3.8405x over previous
//
#include <hip/hip_runtime.h>
#include <hip/hip_bf16.h>

typedef __hip_bfloat16 bf16;
typedef unsigned short u16;
typedef unsigned int u32;

#define DIM 64
#define BN_EPS 1e-5f

struct ParamPack {
    const void* p[18];
    int n[18];
    int off[18];
};

// ---- read element i of p as float, interpreting per flag (1=bf16, 0=f32) ----
__device__ __forceinline__ float load_as(const void* p, int i, int isbf16) {
    if (isbf16) {
        unsigned short b = ((const unsigned short*)p)[i];
        unsigned int u = ((unsigned int)b) << 16;
        return __uint_as_float(u);
    }
    return ((const float*)p)[i];
}

__device__ __forceinline__ float bf2f(unsigned short b) {
    unsigned int u = ((unsigned int)b) << 16;
    return __uint_as_float(u);
}

// round-to-nearest-even f32 -> bf16 bits (finite values only)
__device__ __forceinline__ unsigned short f2bf(float f) {
    unsigned int u = __float_as_uint(f);
    unsigned int r = u + 0x7fff + ((u >> 16) & 1);
    return (unsigned short)(r >> 16);
}

// ---- dtype detect: scan w1a (values uniform in +-0.125). bf16 interp of real
// bf16 data passes ~100%; bf16 interp of f32 bits passes ~55%. ----
__global__ void gin_detect(const void* w, int nelem, int* flag) {
    const unsigned short* u = (const unsigned short*)w;
    int tid = threadIdx.x;
    int cnt = 0;
    for (int i = tid; i < nelem; i += blockDim.x) {
        unsigned int f = ((unsigned int)u[i]) << 16;
        float v = __uint_as_float(f);
        float av = fabsf(v);
        if (av <= 0.126f && (av == 0.0f || av >= 1e-8f)) cnt++;
    }
    __shared__ int sc[256];
    sc[tid] = cnt;
    __syncthreads();
    for (int s = 128; s > 0; s >>= 1) {
        if (tid < s) sc[tid] += sc[tid + s];
        __syncthreads();
    }
    if (tid == 0) flag[0] = (sc[0] * 10 >= nelem * 9) ? 1 : 0;
}

// ---- stage all 18 param tensors into f32 workspace ----
__global__ void gin_cvt_params(ParamPack pk, float* __restrict__ out,
                               const int* __restrict__ flag) {
    int b = blockIdx.x;
    int f = flag[0];
    const void* p = pk.p[b];
    float* o = out + pk.off[b];
    int n = pk.n[b];
    for (int i = threadIdx.x; i < n; i += blockDim.x) o[i] = load_as(p, i, f);
}

// ---- x -> bf16 h, vectorized 4/thread (named with problem identifier) ----
__global__ void GINEncoder_16114717295311_kernel(const void* __restrict__ x,
                                                 u16* __restrict__ h, int n4,
                                                 const int* __restrict__ flag) {
    int i = blockIdx.x * blockDim.x + threadIdx.x;   // group-of-4 index
    int f = flag[0];
    if (i < n4) {
        ushort4 o;
        if (f) {
            o = ((const ushort4*)x)[i];
        } else {
            float4 v = ((const float4*)x)[i];
            o.x = f2bf(v.x); o.y = f2bf(v.y); o.z = f2bf(v.z); o.w = f2bf(v.w);
        }
        ((ushort4*)h)[i] = o;
    }
}

__global__ void gin_zero(float* __restrict__ p, int n) {
    int i = blockIdx.x * blockDim.x + threadIdx.x;
    if (i < n) p[i] = 0.0f;
}

// ======================= CSR build (once; graph reused 3x) =======================
// History: r3 random fill = 17x write amp (107 MB); r4 multi-pass = rescans,
// slower; r5 direct global atomics onto bucket addrs = 431 us contention;
// r10 flat-edge LDS-f32-atomic gather = 639 us (hipcc lowers float atomicAdd
// on LDS to a CAS loop -> lgkmcnt serialization). KEPT structure = r7/r9:
// LDS-privatized bucket histogram + block-local multi-split scatter +
// per-bucket block-local CSR fill (no global atomics in fill). shift=8:
// mscatter per-bucket write runs ~31 edges (~250 B) -> fewer split lines.

// bucket-count histogram, LDS-privatized (one flush atomic per block+bucket)
__global__ void gin_bhist(const int* __restrict__ dst, int* __restrict__ bcnt,
                          int E, int shift, int nbuck) {
    __shared__ int lh[2048];
    int tid = threadIdx.x;
    for (int i = tid; i < nbuck; i += 256) lh[i] = 0;
    __syncthreads();
    int stride = gridDim.x * 256;
    for (int e = blockIdx.x * 256 + tid; e < E; e += stride)
        atomicAdd(&lh[dst[e] >> shift], 1);
    __syncthreads();
    for (int i = tid; i < nbuck; i += 256) {
        int c = lh[i];
        if (c) atomicAdd(&bcnt[i], c);
    }
}

// single block, exclusive scan over up to 2048 ints (in place)
__global__ void gin_scan2(int* __restrict__ part, int NB) {
    __shared__ int lds[256];
    int tid = threadIdx.x;
    int base = tid * 8;
    int a[8];
    int s = 0;
    #pragma unroll
    for (int k = 0; k < 8; k++) {
        a[k] = (base + k < NB) ? part[base + k] : 0;
        s += a[k];
    }
    lds[tid] = s;
    __syncthreads();
    for (int off = 1; off < 256; off <<= 1) {
        int v = (tid >= off) ? lds[tid - off] : 0;
        __syncthreads();
        lds[tid] += v;
        __syncthreads();
    }
    int p = lds[tid] - s;  // exclusive prefix
    #pragma unroll
    for (int k = 0; k < 8; k++) {
        if (base + k < NB) { part[base + k] = p; p += a[k]; }
    }
}

// block-local multi-split scatter: each block takes MS_CHUNK contiguous edges,
// computes per-bucket local positions in LDS, reserves bucket space with ONE
// global atomic per (block,bucket), then writes (src,dst) bucket-grouped.
#define MS_CHUNK 12288
__global__ void gin_mscatter(const int* __restrict__ src, const int* __restrict__ dst,
                             const int* __restrict__ bbase, int* __restrict__ bcur,
                             int2* __restrict__ ebuf, int E, int shift, int nbuck) {
    __shared__ unsigned short spos[MS_CHUNK];  // 24 KB
    __shared__ int lcnt[2048];                 // 8 KB
    __shared__ int lbase[2048];                // 8 KB
    int tid = threadIdx.x;  // 512
    int e0 = blockIdx.x * MS_CHUNK;
    int ecnt = min(MS_CHUNK, E - e0);
    for (int i = tid; i < nbuck; i += 512) lcnt[i] = 0;
    __syncthreads();
    for (int i = tid; i < ecnt; i += 512) {
        int b = dst[e0 + i] >> shift;
        spos[i] = (unsigned short)atomicAdd(&lcnt[b], 1);
    }
    __syncthreads();
    for (int i = tid; i < nbuck; i += 512) {
        int c = lcnt[i];
        lbase[i] = c ? (bbase[i] + atomicAdd(&bcur[i], c)) : 0;
    }
    __syncthreads();
    for (int i = tid; i < ecnt; i += 512) {
        int d = dst[e0 + i];
        int b = d >> shift;
        ebuf[lbase[b] + spos[i]] = make_int2(src[e0 + i], d);
    }
}

// per-bucket CSR fill: block b owns nodes [b<<shift, ...+W) and the contiguous
// ebuf slice [bbase[b], bbase[b+1]). Local deg histogram + local scan in LDS,
// rowptr written directly, adj scattered into a contiguous window.
// NO global atomics (int LDS atomics only -- native, unlike f32).
#define MAXW 2048
__global__ void gin_bfill(const int2* __restrict__ ebuf, const int* __restrict__ bbase,
                          int* __restrict__ rowptr, int* __restrict__ adj,
                          int E, int N, int shift, int nbuck) {
    __shared__ int lcnt[MAXW];
    __shared__ int lptr[MAXW];
    __shared__ int tsum[256];
    int b = blockIdx.x;
    int lo = b << shift;
    int W = min(1 << shift, N - lo);
    int tid = threadIdx.x;  // 256
    int base = bbase[b];
    int end = (b + 1 < nbuck) ? bbase[b + 1] : E;
    int cnt = end - base;

    for (int i = tid; i < W; i += 256) lcnt[i] = 0;
    __syncthreads();
    for (int i = tid; i < cnt; i += 256)
        atomicAdd(&lcnt[ebuf[base + i].y - lo], 1);
    __syncthreads();

    // exclusive scan of lcnt[0..W): per-thread chunk + Hillis-Steele over totals
    int per = (W + 255) >> 8;
    int i0 = tid * per;
    int s = 0;
    for (int k = 0; k < per; k++) {
        int i = i0 + k;
        if (i < W) { int t = lcnt[i]; lptr[i] = s; s += t; }
    }
    tsum[tid] = s;
    __syncthreads();
    for (int off = 1; off < 256; off <<= 1) {
        int v = (tid >= off) ? tsum[tid - off] : 0;
        __syncthreads();
        tsum[tid] += v;
        __syncthreads();
    }
    int tb = tsum[tid] - s;  // exclusive thread base
    for (int k = 0; k < per; k++) {
        int i = i0 + k;
        if (i < W) {
            int g = base + tb + lptr[i];
            lptr[i] = g;             // global adj base for node lo+i
            rowptr[lo + i] = g;
            lcnt[i] = 0;             // reuse as cursor
        }
    }
    if (b == nbuck - 1 && tid == 0) rowptr[N] = E;
    __syncthreads();

    for (int i = tid; i < cnt; i += 256) {
        int2 sd = ebuf[base + i];
        int d = sd.y - lo;
        int pos = atomicAdd(&lcnt[d], 1);   // LDS int atomic
        adj[lptr[d] + pos] = sd.x;
    }
}

// ======================= per-layer fused kernel =======================

// Fused gather + MLP, v6 = r9's proven row-serial paired-row gather (114.6 us)
// + r10's launch eliminations (prev-layer BN affine computed IN-BLOCK from
// pstats -> no gin_ss kernels). r10's flat-edge LDS-f32-atomic gather is
// reverted (float atomicAdd on LDS = CAS loop = 639 us).
//  - h stored bf16 between layers; paired-row gather: lanes 0-31 = row 2p,
//    lanes 32-63 = row 2p+1, each lane loads a uint = 2 channels (one load
//    covers 2 rows x 128 B -- full cache lines, loads halved vs 1-row).
//  - GEMM/BN stats f32; layer 3 writes f32 (outf32=1) for the pool.
// 512 thr / 8 waves, LDS ~38.4 KB -> 4 blocks/CU, 32 waves/CU.
__global__ void gin_gmlp(const u16* __restrict__ hin, void* __restrict__ hout,
                         const int* __restrict__ rowptr, const int* __restrict__ adj,
                         const float* __restrict__ pstats, const float* __restrict__ pgamma,
                         const float* __restrict__ pbeta,
                         const float* __restrict__ Wa, const float* __restrict__ Ba,
                         const float* __restrict__ Wb, const float* __restrict__ Bb,
                         float* __restrict__ stats, int N, float invN, int outf32) {
    __shared__ float sW[DIM * DIM];     // 16 KB, Wa then Wb
    __shared__ float sT[64][DIM + 4];   // 17 KB; +4 pad keeps rows 16B-aligned
    __shared__ float sBa[DIM], sBb[DIM], sSS[2 * DIM];
    __shared__ float sred[8][16][8];    // 4 KB

    int tid = threadIdx.x;              // 512
    int lane = tid & 63, wave = tid >> 6;
    int rbase = blockIdx.x * 64;

    for (int i = tid; i < DIM * DIM; i += 512) sW[i] = Wa[i];
    if (tid < DIM) { sBa[tid] = Ba[tid]; sBb[tid] = Bb[tid]; }
    if (tid >= 64 && tid < 128) {
        int d = tid - 64;
        float sc = 1.f, sh = 0.f;
        if (pstats) {
            float m = pstats[d] * invN;
            float var = pstats[DIM + d] * invN - m * m;
            sc = pgamma[d] * rsqrtf(var + BN_EPS);
            sh = pbeta[d] - sc * m;
        }
        sSS[d] = sc; sSS[DIM + d] = sh;
    }
    __syncthreads();   // sSS visible to all waves before gather

    // ---- phase 1: paired-row gather into LDS tile ----
    {
        int half = lane >> 5;           // 0: even row, 1: odd row
        int c = lane & 31;              // channel-pair index (channels 2c, 2c+1)
        float2 sc = *(const float2*)&sSS[2 * c];
        float2 sh = *(const float2*)&sSS[DIM + 2 * c];
        for (int pi = wave; pi < 32; pi += 8) {
            int rr = 2 * pi + half;
            int row = rbase + rr;
            float v0 = 0.f, v1 = 0.f;
            float degp1 = 0.f;
            if (row < N) {
                int rb = rowptr[row], re = rowptr[row + 1];
                degp1 = (float)(re - rb + 1);
                unsigned int u = *(const unsigned int*)&hin[(size_t)row * DIM + 2 * c];
                v0 = bf2f((unsigned short)u);
                v1 = bf2f((unsigned short)(u >> 16));
                int j = rb;
                for (; j + 8 <= re; j += 8) {
                    int s0 = adj[j], s1 = adj[j + 1], s2 = adj[j + 2], s3 = adj[j + 3];
                    int s4 = adj[j + 4], s5 = adj[j + 5], s6 = adj[j + 6], s7 = adj[j + 7];
                    unsigned int u0 = *(const unsigned int*)&hin[(size_t)s0 * DIM + 2 * c];
                    unsigned int u1 = *(const unsigned int*)&hin[(size_t)s1 * DIM + 2 * c];
                    unsigned int u2 = *(const unsigned int*)&hin[(size_t)s2 * DIM + 2 * c];
                    unsigned int u3 = *(const unsigned int*)&hin[(size_t)s3 * DIM + 2 * c];
                    unsigned int u4 = *(const unsigned int*)&hin[(size_t)s4 * DIM + 2 * c];
                    unsigned int u5 = *(const unsigned int*)&hin[(size_t)s5 * DIM + 2 * c];
                    unsigned int u6 = *(const unsigned int*)&hin[(size_t)s6 * DIM + 2 * c];
                    unsigned int u7 = *(const unsigned int*)&hin[(size_t)s7 * DIM + 2 * c];
                    v0 += ((bf2f((u16)u0) + bf2f((u16)u1)) + (bf2f((u16)u2) + bf2f((u16)u3)))
                        + ((bf2f((u16)u4) + bf2f((u16)u5)) + (bf2f((u16)u6) + bf2f((u16)u7)));
                    v1 += ((bf2f((u16)(u0 >> 16)) + bf2f((u16)(u1 >> 16)))
                         + (bf2f((u16)(u2 >> 16)) + bf2f((u16)(u3 >> 16))))
                        + ((bf2f((u16)(u4 >> 16)) + bf2f((u16)(u5 >> 16)))
                         + (bf2f((u16)(u6 >> 16)) + bf2f((u16)(u7 >> 16))));
                }
                for (; j < re; j++) {
                    int s = adj[j];
                    unsigned int uu = *(const unsigned int*)&hin[(size_t)s * DIM + 2 * c];
                    v0 += bf2f((u16)uu);
                    v1 += bf2f((u16)(uu >> 16));
                }
            }
            float2 o;
            o.x = sc.x * v0 + degp1 * sh.x;
            o.y = sc.y * v1 + degp1 * sh.y;
            *(float2*)&sT[rr][2 * c] = o;
        }
    }
    __syncthreads();

    // ---- phase 2: GEMM pair, each thread owns rows r0..r0+1 x cols c0..c0+3
    int tx = tid & 15, ty = tid >> 4;   // ty 0..31
    int c0 = tx * 4;
    int r0 = ty * 2;
    float acc[2][4];

    // GEMM1: mid = relu(tile @ Wa + Ba)
    {
        float4 bia = *(const float4*)&sBa[c0];
        #pragma unroll
        for (int i = 0; i < 2; i++) {
            acc[i][0] = bia.x; acc[i][1] = bia.y; acc[i][2] = bia.z; acc[i][3] = bia.w;
        }
    }
    #pragma unroll 8
    for (int k = 0; k < DIM; k++) {
        float4 b = *(const float4*)&sW[k * DIM + c0];
        float a0 = sT[r0 + 0][k], a1 = sT[r0 + 1][k];
        acc[0][0] = fmaf(a0, b.x, acc[0][0]); acc[0][1] = fmaf(a0, b.y, acc[0][1]);
        acc[0][2] = fmaf(a0, b.z, acc[0][2]); acc[0][3] = fmaf(a0, b.w, acc[0][3]);
        acc[1][0] = fmaf(a1, b.x, acc[1][0]); acc[1][1] = fmaf(a1, b.y, acc[1][1]);
        acc[1][2] = fmaf(a1, b.z, acc[1][2]); acc[1][3] = fmaf(a1, b.w, acc[1][3]);
    }
    __syncthreads();  // all GEMM1 reads of sT and sW done

    // mid -> sT; reload sW = Wb (overlaps)
    #pragma unroll
    for (int i = 0; i < 2; i++) {
        float4 m;
        m.x = fmaxf(acc[i][0], 0.f); m.y = fmaxf(acc[i][1], 0.f);
        m.z = fmaxf(acc[i][2], 0.f); m.w = fmaxf(acc[i][3], 0.f);
        *(float4*)&sT[r0 + i][c0] = m;
    }
    for (int i = tid; i < DIM * DIM; i += 512) sW[i] = Wb[i];
    __syncthreads();

    // GEMM2: out = relu(mid @ Wb + Bb)
    {
        float4 bib = *(const float4*)&sBb[c0];
        #pragma unroll
        for (int i = 0; i < 2; i++) {
            acc[i][0] = bib.x; acc[i][1] = bib.y; acc[i][2] = bib.z; acc[i][3] = bib.w;
        }
    }
    #pragma unroll 8
    for (int k = 0; k < DIM; k++) {
        float4 b = *(const float4*)&sW[k * DIM + c0];
        float a0 = sT[r0 + 0][k], a1 = sT[r0 + 1][k];
        acc[0][0] = fmaf(a0, b.x, acc[0][0]); acc[0][1] = fmaf(a0, b.y, acc[0][1]);
        acc[0][2] = fmaf(a0, b.z, acc[0][2]); acc[0][3] = fmaf(a0, b.w, acc[0][3]);
        acc[1][0] = fmaf(a1, b.x, acc[1][0]); acc[1][1] = fmaf(a1, b.y, acc[1][1]);
        acc[1][2] = fmaf(a1, b.z, acc[1][2]); acc[1][3] = fmaf(a1, b.w, acc[1][3]);
    }

    // relu, store (bf16 or f32), per-thread BN partials (valid rows only)
    float s[4] = {0.f, 0.f, 0.f, 0.f}, q[4] = {0.f, 0.f, 0.f, 0.f};
    #pragma unroll
    for (int i = 0; i < 2; i++) {
        int r = rbase + r0 + i;
        float4 o;
        o.x = fmaxf(acc[i][0], 0.f); o.y = fmaxf(acc[i][1], 0.f);
        o.z = fmaxf(acc[i][2], 0.f); o.w = fmaxf(acc[i][3], 0.f);
        if (r < N) {
            if (outf32) {
                *(float4*)&((float*)hout)[(size_t)r * DIM + c0] = o;
            } else {
                ushort4 ub;
                ub.x = f2bf(o.x); ub.y = f2bf(o.y); ub.z = f2bf(o.z); ub.w = f2bf(o.w);
                *(ushort4*)&((u16*)hout)[(size_t)r * DIM + c0] = ub;
            }
            s[0] += o.x; q[0] += o.x * o.x;
            s[1] += o.y; q[1] += o.y * o.y;
            s[2] += o.z; q[2] += o.z * o.z;
            s[3] += o.w; q[3] += o.w * o.w;
        }
    }
    // reduce over the row-groups within each wave: lanes +16, +32
    #pragma unroll
    for (int j = 0; j < 4; j++) {
        s[j] += __shfl_xor(s[j], 16); s[j] += __shfl_xor(s[j], 32);
        q[j] += __shfl_xor(q[j], 16); q[j] += __shfl_xor(q[j], 32);
    }
    if (lane < 16) {
        #pragma unroll
        for (int j = 0; j < 4; j++) {
            sred[wave][lane][j] = s[j];
            sred[wave][lane][4 + j] = q[j];
        }
    }
    __syncthreads();
    if (tid < DIM) {
        int txx = tid >> 2, j = tid & 3;
        float as = 0.f, aq = 0.f;
        #pragma unroll
        for (int w = 0; w < 8; w++) {
            as += sred[w][txx][j];
            aq += sred[w][txx][4 + j];
        }
        atomicAdd(&stats[tid], as);
        atomicAdd(&stats[DIM + tid], aq);
    }
}

// pool with folded BN3 (affine computed inline from stats3): one wave per graph
// (batch sorted -> binary search range), direct write to d_out. No atomics.
__global__ void gin_pool(const float* __restrict__ h, const int* __restrict__ batch,
                         const float* __restrict__ stats, const float* __restrict__ gamma,
                         const float* __restrict__ beta, float invN,
                         void* __restrict__ out, int N, int G,
                         const int* __restrict__ flag) {
    int gw = (blockIdx.x * blockDim.x + threadIdx.x) >> 6;
    int lane = threadIdx.x & 63;
    if (gw >= G) return;
    float m = stats[lane] * invN;
    float var = stats[DIM + lane] * invN - m * m;
    float sc = gamma[lane] * rsqrtf(var + BN_EPS);
    float sh = beta[lane] - sc * m;
    int lo = 0, hi = N;
    while (lo < hi) { int mid = (lo + hi) >> 1; if (batch[mid] < gw) lo = mid + 1; else hi = mid; }
    int s0 = lo;
    hi = N;
    while (lo < hi) { int mid = (lo + hi) >> 1; if (batch[mid] < gw + 1) lo = mid + 1; else hi = mid; }
    int s1 = lo;
    float a0 = 0.f, a1 = 0.f, a2 = 0.f, a3 = 0.f;
    int n = s0;
    for (; n + 3 < s1; n += 4) {
        a0 += h[n * DIM + lane];
        a1 += h[(n + 1) * DIM + lane];
        a2 += h[(n + 2) * DIM + lane];
        a3 += h[(n + 3) * DIM + lane];
    }
    for (; n < s1; n++) a0 += h[n * DIM + lane];
    float acc = (a0 + a1) + (a2 + a3);
    float v = sc * acc + (float)(s1 - s0) * sh;
    int f = flag[0];
    if (f) ((bf16*)out)[gw * DIM + lane] = __float2bfloat16(v);
    else   ((float*)out)[gw * DIM + lane] = v;
}

extern "C" void kernel_launch(void* const* d_in, const int* in_sizes, int n_in,
                              void* d_out, int out_size, void* d_ws, size_t ws_size,
                              hipStream_t stream) {
    (void)hipGetLastError();  // clear any stale error

    const int N = in_sizes[0] / DIM;   // F_IN == DIM == 64
    const int E = in_sizes[1] / 2;
    const int G = out_size / DIM;
    const size_t ND = (size_t)N * DIM;

    const void* x     = d_in[0];
    const int*  ei    = (const int*)d_in[1];
    const int*  srcp  = ei;
    const int*  dstp  = ei + E;
    const int*  batch = (const int*)d_in[2];

    // bucket shift: start at 8 (250-B mscatter runs); NBUCK <= 2048, W <= MAXW
    int SHIFT = 8;
    while ((((N - 1) >> SHIFT) + 1) > 2048) SHIFT++;
    const int NBUCK = ((N - 1) >> SHIFT) + 1;   // N=100k -> 391

    // workspace layout (4-B units from d_ws)
    int*   flag   = (int*)d_ws;                  // [64]
    float* P      = (float*)d_ws + 64;           // [25600] staged f32 params
    int*   bcnt   = (int*)(P + 25600);           // [2048] counts -> bases
    int*   bcur   = bcnt + 2048;                 // [2048] reservation cursors
    float* stats  = (float*)(bcur + 2048);       // [384] = 3 layers x 128
    int*   rowptr = (int*)(stats + 384);         // [N+1]
    int*   adj    = rowptr + (N + 1);            // [E]
    size_t ha4    = ((size_t)(adj - (int*)d_ws) + (size_t)E + 3) & ~(size_t)3;
    u16*   hA     = (u16*)((int*)d_ws + ha4);    // [ND] bf16 (16-B aligned)
    u16*   hB     = hA + ND;                     // [ND] bf16
    float* F      = (float*)(hA + 2 * ND);       // [ND] f32 (layer-3 out)
    int2*  ebuf   = (int2*)hA;                   // [E] aliases h region (CSR build
                                                 // runs BEFORE x-convert)
    size_t need   = (char*)(F + ND) - (char*)d_ws;
    if (ws_size < need || NBUCK > 2048 || (1 << SHIFT) > MAXW) {
        hipMemsetAsync(d_out, 0x77, (size_t)out_size * 2, stream);  // ~5e33 marker
        return;
    }

    // param staging pack: per layer {wa, ba, wb, bb, gamma, beta}
    ParamPack pk;
    int off = 0;
    for (int l = 0; l < 3; l++) {
        for (int j = 0; j < 6; j++) {
            int idx = 3 + 6 * l + j;
            pk.p[6 * l + j]   = d_in[idx];
            pk.n[6 * l + j]   = in_sizes[idx];
            pk.off[6 * l + j] = off;
            off += in_sizes[idx];
        }
    }
    float* wa[3], *ba[3], *wb[3], *bb[3], *gm[3], *be[3];
    for (int l = 0; l < 3; l++) {
        float* base = P + l * 8448;
        wa[l] = base;        ba[l] = base + 4096;
        wb[l] = base + 4160; bb[l] = base + 8256;
        gm[l] = base + 8320; be[l] = base + 8384;
    }

    const int TB = 256;
    const int grid_nd4 = (int)((ND / 4 + TB - 1) / TB);
    const int grid_g   = (G * DIM + TB - 1) / TB;
    const int grid_mlp = (N + 63) / 64;
    const int grid_ms  = (E + MS_CHUNK - 1) / MS_CHUNK;
    const float invN   = 1.0f / (float)N;

    gin_detect<<<1, 256, 0, stream>>>(d_in[3], in_sizes[3], flag);
    gin_cvt_params<<<18, 256, 0, stream>>>(pk, P, flag);

    // ---- CSR build (once; ebuf aliases h region, so build before x-convert) ----
    gin_zero<<<18, TB, 0, stream>>>((float*)bcnt, 2048 + 2048 + 384);  // bcnt|bcur|stats
    gin_bhist<<<256, 256, 0, stream>>>(dstp, bcnt, E, SHIFT, NBUCK);
    gin_scan2<<<1, 256, 0, stream>>>(bcnt, NBUCK);                     // -> excl. bases
    gin_mscatter<<<grid_ms, 512, 0, stream>>>(srcp, dstp, bcnt, bcur, ebuf, E, SHIFT, NBUCK);
    gin_bfill<<<NBUCK, 256, 0, stream>>>(ebuf, bcnt, rowptr, adj, E, N, SHIFT, NBUCK);

    // x -> bf16 h (after CSR build; hA aliased ebuf)
    GINEncoder_16114717295311_kernel<<<grid_nd4, TB, 0, stream>>>(x, hA, (int)(ND / 4), flag);

    // L1: hA -> hB (identity affine), L2: hB -> hA, L3: hA -> F (f32)
    gin_gmlp<<<grid_mlp, 512, 0, stream>>>(hA, hB, rowptr, adj,
                                           nullptr, nullptr, nullptr,
                                           wa[0], ba[0], wb[0], bb[0],
                                           stats + 0, N, invN, 0);
    gin_gmlp<<<grid_mlp, 512, 0, stream>>>(hB, hA, rowptr, adj,
                                           stats + 0, gm[0], be[0],
                                           wa[1], ba[1], wb[1], bb[1],
                                           stats + 128, N, invN, 0);
    gin_gmlp<<<grid_mlp, 512, 0, stream>>>(hA, F, rowptr, adj,
                                           stats + 128, gm[1], be[1],
                                           wa[2], ba[2], wb[2], bb[2],
                                           stats + 256, N, invN, 1);

    gin_pool<<<grid_g, TB, 0, stream>>>(F, batch, stats + 256, gm[2], be[2], invN,
                                        d_out, N, G, flag);

    // "some launch failed" marker: err prints ~1.7e38 (bf16) / 3.4e38 (f32)
    hipError_t e = hipGetLastError();
    if (e != hipSuccess) {
        hipMemsetAsync(d_out, 0x7F, (size_t)out_size * 2, stream);
    }
}

// Round 12
// 526.754 us; speedup vs baseline: 3.9122x; 1.0187x over previous
//
#include <hip/hip_runtime.h>
#include <hip/hip_bf16.h>

typedef __hip_bfloat16 bf16;
typedef unsigned short u16;
typedef unsigned int u32;

#define DIM 64
#define BN_EPS 1e-5f

struct ParamPack {
    const void* p[18];
    int n[18];
    int off[18];
};

// ---- read element i of p as float, interpreting per flag (1=bf16, 0=f32) ----
__device__ __forceinline__ float load_as(const void* p, int i, int isbf16) {
    if (isbf16) {
        unsigned short b = ((const unsigned short*)p)[i];
        unsigned int u = ((unsigned int)b) << 16;
        return __uint_as_float(u);
    }
    return ((const float*)p)[i];
}

__device__ __forceinline__ float bf2f(unsigned short b) {
    unsigned int u = ((unsigned int)b) << 16;
    return __uint_as_float(u);
}

// round-to-nearest-even f32 -> bf16 bits (finite values only)
__device__ __forceinline__ unsigned short f2bf(float f) {
    unsigned int u = __float_as_uint(f);
    unsigned int r = u + 0x7fff + ((u >> 16) & 1);
    return (unsigned short)(r >> 16);
}

// ---- stage all 18 param tensors into f32 workspace; dtype-detect fused in
// (each block re-scans w1a locally -- 8 KB, free; block 0 publishes flag for
// the later x-convert / pool kernels). Detect: w1a uniform in +-0.125; bf16
// interp of real bf16 data passes ~100%, of f32 bits ~55%. ----
__global__ void gin_cvt_params(ParamPack pk, float* __restrict__ out,
                               const unsigned short* __restrict__ w, int wn,
                               int* __restrict__ flag) {
    __shared__ int sc[256];
    int tid = threadIdx.x;
    int cnt = 0;
    for (int i = tid; i < wn; i += 256) {
        unsigned int fb = ((unsigned int)w[i]) << 16;
        float av = fabsf(__uint_as_float(fb));
        if (av <= 0.126f && (av == 0.0f || av >= 1e-8f)) cnt++;
    }
    sc[tid] = cnt;
    __syncthreads();
    for (int s = 128; s > 0; s >>= 1) {
        if (tid < s) sc[tid] += sc[tid + s];
        __syncthreads();
    }
    int f = (sc[0] * 10 >= wn * 9) ? 1 : 0;
    if (blockIdx.x == 0 && tid == 0) flag[0] = f;

    int b = blockIdx.x;
    const void* p = pk.p[b];
    float* o = out + pk.off[b];
    int n = pk.n[b];
    for (int i = tid; i < n; i += 256) o[i] = load_as(p, i, f);
}

// ---- x -> bf16 h, vectorized 4/thread (named with problem identifier) ----
__global__ void GINEncoder_16114717295311_kernel(const void* __restrict__ x,
                                                 u16* __restrict__ h, int n4,
                                                 const int* __restrict__ flag) {
    int i = blockIdx.x * blockDim.x + threadIdx.x;   // group-of-4 index
    int f = flag[0];
    if (i < n4) {
        ushort4 o;
        if (f) {
            o = ((const ushort4*)x)[i];
        } else {
            float4 v = ((const float4*)x)[i];
            o.x = f2bf(v.x); o.y = f2bf(v.y); o.z = f2bf(v.z); o.w = f2bf(v.w);
        }
        ((ushort4*)h)[i] = o;
    }
}

__global__ void gin_zero(float* __restrict__ p, int n) {
    int i = blockIdx.x * blockDim.x + threadIdx.x;
    if (i < n) p[i] = 0.0f;
}

// ======================= CSR build (once; graph reused 3x) =======================
// History: r3 random fill = 17x write amp (107 MB); r4 multi-pass = rescans,
// slower; r5 direct global atomics onto bucket addrs = 431 us contention;
// r10 flat-edge LDS-f32-atomic gather = 639 us (hipcc lowers float atomicAdd
// on LDS to a CAS loop). KEPT structure = r7/r9/r11: LDS-privatized bucket
// histogram + block-local multi-split scatter + per-bucket block-local fill.
// r12: ebuf compressed int2 -> u32 ((src<<SHIFT) | dst-offset) -- halves
// mscatter WRITE and bfill FETCH.

// bucket-count histogram, LDS-privatized (one flush atomic per block+bucket)
__global__ void gin_bhist(const int* __restrict__ dst, int* __restrict__ bcnt,
                          int E, int shift, int nbuck) {
    __shared__ int lh[2048];
    int tid = threadIdx.x;
    for (int i = tid; i < nbuck; i += 256) lh[i] = 0;
    __syncthreads();
    int stride = gridDim.x * 256;
    for (int e = blockIdx.x * 256 + tid; e < E; e += stride)
        atomicAdd(&lh[dst[e] >> shift], 1);
    __syncthreads();
    for (int i = tid; i < nbuck; i += 256) {
        int c = lh[i];
        if (c) atomicAdd(&bcnt[i], c);
    }
}

// single block, exclusive scan over up to 2048 ints (in place)
__global__ void gin_scan2(int* __restrict__ part, int NB) {
    __shared__ int lds[256];
    int tid = threadIdx.x;
    int base = tid * 8;
    int a[8];
    int s = 0;
    #pragma unroll
    for (int k = 0; k < 8; k++) {
        a[k] = (base + k < NB) ? part[base + k] : 0;
        s += a[k];
    }
    lds[tid] = s;
    __syncthreads();
    for (int off = 1; off < 256; off <<= 1) {
        int v = (tid >= off) ? lds[tid - off] : 0;
        __syncthreads();
        lds[tid] += v;
        __syncthreads();
    }
    int p = lds[tid] - s;  // exclusive prefix
    #pragma unroll
    for (int k = 0; k < 8; k++) {
        if (base + k < NB) { part[base + k] = p; p += a[k]; }
    }
}

// block-local multi-split scatter: each block takes MS_CHUNK contiguous edges,
// computes per-bucket local positions in LDS, reserves bucket space with ONE
// global atomic per (block,bucket), then writes packed (src<<SHIFT)|off
// bucket-grouped (u32 -- half the bytes of int2).
#define MS_CHUNK 12288
__global__ void gin_mscatter(const int* __restrict__ src, const int* __restrict__ dst,
                             const int* __restrict__ bbase, int* __restrict__ bcur,
                             u32* __restrict__ ebuf, int E, int shift, int nbuck) {
    __shared__ unsigned short spos[MS_CHUNK];  // 24 KB
    __shared__ int lcnt[2048];                 // 8 KB
    __shared__ int lbase[2048];                // 8 KB
    int tid = threadIdx.x;  // 512
    int e0 = blockIdx.x * MS_CHUNK;
    int ecnt = min(MS_CHUNK, E - e0);
    u32 mask = (1u << shift) - 1u;
    for (int i = tid; i < nbuck; i += 512) lcnt[i] = 0;
    __syncthreads();
    for (int i = tid; i < ecnt; i += 512) {
        int b = dst[e0 + i] >> shift;
        spos[i] = (unsigned short)atomicAdd(&lcnt[b], 1);
    }
    __syncthreads();
    for (int i = tid; i < nbuck; i += 512) {
        int c = lcnt[i];
        lbase[i] = c ? (bbase[i] + atomicAdd(&bcur[i], c)) : 0;
    }
    __syncthreads();
    for (int i = tid; i < ecnt; i += 512) {
        int d = dst[e0 + i];
        int b = d >> shift;
        ebuf[lbase[b] + spos[i]] = ((u32)src[e0 + i] << shift) | ((u32)d & mask);
    }
}

// per-bucket CSR fill: block b owns nodes [b<<shift, ...+W) and the contiguous
// ebuf slice [bbase[b], bbase[b+1]). Local deg histogram + local scan in LDS,
// rowptr written directly, adj scattered into a contiguous window.
// NO global atomics (int LDS atomics only -- native, unlike f32).
#define MAXW 2048
__global__ void gin_bfill(const u32* __restrict__ ebuf, const int* __restrict__ bbase,
                          int* __restrict__ rowptr, int* __restrict__ adj,
                          int E, int N, int shift, int nbuck) {
    __shared__ int lcnt[MAXW];
    __shared__ int lptr[MAXW];
    __shared__ int tsum[256];
    int b = blockIdx.x;
    int lo = b << shift;
    int W = min(1 << shift, N - lo);
    int tid = threadIdx.x;  // 256
    int base = bbase[b];
    int end = (b + 1 < nbuck) ? bbase[b + 1] : E;
    int cnt = end - base;
    u32 mask = (1u << shift) - 1u;

    for (int i = tid; i < W; i += 256) lcnt[i] = 0;
    __syncthreads();
    for (int i = tid; i < cnt; i += 256)
        atomicAdd(&lcnt[ebuf[base + i] & mask], 1);
    __syncthreads();

    // exclusive scan of lcnt[0..W): per-thread chunk + Hillis-Steele over totals
    int per = (W + 255) >> 8;
    int i0 = tid * per;
    int s = 0;
    for (int k = 0; k < per; k++) {
        int i = i0 + k;
        if (i < W) { int t = lcnt[i]; lptr[i] = s; s += t; }
    }
    tsum[tid] = s;
    __syncthreads();
    for (int off = 1; off < 256; off <<= 1) {
        int v = (tid >= off) ? tsum[tid - off] : 0;
        __syncthreads();
        tsum[tid] += v;
        __syncthreads();
    }
    int tb = tsum[tid] - s;  // exclusive thread base
    for (int k = 0; k < per; k++) {
        int i = i0 + k;
        if (i < W) {
            int g = base + tb + lptr[i];
            lptr[i] = g;             // global adj base for node lo+i
            rowptr[lo + i] = g;
            lcnt[i] = 0;             // reuse as cursor
        }
    }
    if (b == nbuck - 1 && tid == 0) rowptr[N] = E;
    __syncthreads();

    for (int i = tid; i < cnt; i += 256) {
        u32 e = ebuf[base + i];
        int d = (int)(e & mask);
        int pos = atomicAdd(&lcnt[d], 1);   // LDS int atomic
        adj[lptr[d] + pos] = (int)(e >> shift);
    }
}

// ======================= per-layer fused kernel =======================

// Fused gather + MLP, v7 = r11's v6 with bf16 output for ALL layers (the f32
// layer-3 buffer is gone; pool reads bf16 -> L3 WRITE and pool READ halved).
//  - h stored bf16 between layers; paired-row gather: lanes 0-31 = row 2p,
//    lanes 32-63 = row 2p+1, each lane loads a uint = 2 channels (one load
//    covers 2 rows x 128 B -- full cache lines).
//  - prev-layer BN affine computed IN-BLOCK from pstats (no gin_ss kernels).
//  - GEMM/BN stats f32 in LDS/regs.
// 512 thr / 8 waves, LDS ~38.4 KB -> 4 blocks/CU, 32 waves/CU.
__global__ void gin_gmlp(const u16* __restrict__ hin, u16* __restrict__ hout,
                         const int* __restrict__ rowptr, const int* __restrict__ adj,
                         const float* __restrict__ pstats, const float* __restrict__ pgamma,
                         const float* __restrict__ pbeta,
                         const float* __restrict__ Wa, const float* __restrict__ Ba,
                         const float* __restrict__ Wb, const float* __restrict__ Bb,
                         float* __restrict__ stats, int N, float invN) {
    __shared__ float sW[DIM * DIM];     // 16 KB, Wa then Wb
    __shared__ float sT[64][DIM + 4];   // 17 KB; +4 pad keeps rows 16B-aligned
    __shared__ float sBa[DIM], sBb[DIM], sSS[2 * DIM];
    __shared__ float sred[8][16][8];    // 4 KB

    int tid = threadIdx.x;              // 512
    int lane = tid & 63, wave = tid >> 6;
    int rbase = blockIdx.x * 64;

    for (int i = tid; i < DIM * DIM; i += 512) sW[i] = Wa[i];
    if (tid < DIM) { sBa[tid] = Ba[tid]; sBb[tid] = Bb[tid]; }
    if (tid >= 64 && tid < 128) {
        int d = tid - 64;
        float sc = 1.f, sh = 0.f;
        if (pstats) {
            float m = pstats[d] * invN;
            float var = pstats[DIM + d] * invN - m * m;
            sc = pgamma[d] * rsqrtf(var + BN_EPS);
            sh = pbeta[d] - sc * m;
        }
        sSS[d] = sc; sSS[DIM + d] = sh;
    }
    __syncthreads();   // sSS visible to all waves before gather

    // ---- phase 1: paired-row gather into LDS tile ----
    {
        int half = lane >> 5;           // 0: even row, 1: odd row
        int c = lane & 31;              // channel-pair index (channels 2c, 2c+1)
        float2 sc = *(const float2*)&sSS[2 * c];
        float2 sh = *(const float2*)&sSS[DIM + 2 * c];
        for (int pi = wave; pi < 32; pi += 8) {
            int rr = 2 * pi + half;
            int row = rbase + rr;
            float v0 = 0.f, v1 = 0.f;
            float degp1 = 0.f;
            if (row < N) {
                int rb = rowptr[row], re = rowptr[row + 1];
                degp1 = (float)(re - rb + 1);
                unsigned int u = *(const unsigned int*)&hin[(size_t)row * DIM + 2 * c];
                v0 = bf2f((unsigned short)u);
                v1 = bf2f((unsigned short)(u >> 16));
                int j = rb;
                for (; j + 8 <= re; j += 8) {
                    int s0 = adj[j], s1 = adj[j + 1], s2 = adj[j + 2], s3 = adj[j + 3];
                    int s4 = adj[j + 4], s5 = adj[j + 5], s6 = adj[j + 6], s7 = adj[j + 7];
                    unsigned int u0 = *(const unsigned int*)&hin[(size_t)s0 * DIM + 2 * c];
                    unsigned int u1 = *(const unsigned int*)&hin[(size_t)s1 * DIM + 2 * c];
                    unsigned int u2 = *(const unsigned int*)&hin[(size_t)s2 * DIM + 2 * c];
                    unsigned int u3 = *(const unsigned int*)&hin[(size_t)s3 * DIM + 2 * c];
                    unsigned int u4 = *(const unsigned int*)&hin[(size_t)s4 * DIM + 2 * c];
                    unsigned int u5 = *(const unsigned int*)&hin[(size_t)s5 * DIM + 2 * c];
                    unsigned int u6 = *(const unsigned int*)&hin[(size_t)s6 * DIM + 2 * c];
                    unsigned int u7 = *(const unsigned int*)&hin[(size_t)s7 * DIM + 2 * c];
                    v0 += ((bf2f((u16)u0) + bf2f((u16)u1)) + (bf2f((u16)u2) + bf2f((u16)u3)))
                        + ((bf2f((u16)u4) + bf2f((u16)u5)) + (bf2f((u16)u6) + bf2f((u16)u7)));
                    v1 += ((bf2f((u16)(u0 >> 16)) + bf2f((u16)(u1 >> 16)))
                         + (bf2f((u16)(u2 >> 16)) + bf2f((u16)(u3 >> 16))))
                        + ((bf2f((u16)(u4 >> 16)) + bf2f((u16)(u5 >> 16)))
                         + (bf2f((u16)(u6 >> 16)) + bf2f((u16)(u7 >> 16))));
                }
                for (; j < re; j++) {
                    int s = adj[j];
                    unsigned int uu = *(const unsigned int*)&hin[(size_t)s * DIM + 2 * c];
                    v0 += bf2f((u16)uu);
                    v1 += bf2f((u16)(uu >> 16));
                }
            }
            float2 o;
            o.x = sc.x * v0 + degp1 * sh.x;
            o.y = sc.y * v1 + degp1 * sh.y;
            *(float2*)&sT[rr][2 * c] = o;
        }
    }
    __syncthreads();

    // ---- phase 2: GEMM pair, each thread owns rows r0..r0+1 x cols c0..c0+3
    int tx = tid & 15, ty = tid >> 4;   // ty 0..31
    int c0 = tx * 4;
    int r0 = ty * 2;
    float acc[2][4];

    // GEMM1: mid = relu(tile @ Wa + Ba)
    {
        float4 bia = *(const float4*)&sBa[c0];
        #pragma unroll
        for (int i = 0; i < 2; i++) {
            acc[i][0] = bia.x; acc[i][1] = bia.y; acc[i][2] = bia.z; acc[i][3] = bia.w;
        }
    }
    #pragma unroll 8
    for (int k = 0; k < DIM; k++) {
        float4 b = *(const float4*)&sW[k * DIM + c0];
        float a0 = sT[r0 + 0][k], a1 = sT[r0 + 1][k];
        acc[0][0] = fmaf(a0, b.x, acc[0][0]); acc[0][1] = fmaf(a0, b.y, acc[0][1]);
        acc[0][2] = fmaf(a0, b.z, acc[0][2]); acc[0][3] = fmaf(a0, b.w, acc[0][3]);
        acc[1][0] = fmaf(a1, b.x, acc[1][0]); acc[1][1] = fmaf(a1, b.y, acc[1][1]);
        acc[1][2] = fmaf(a1, b.z, acc[1][2]); acc[1][3] = fmaf(a1, b.w, acc[1][3]);
    }
    __syncthreads();  // all GEMM1 reads of sT and sW done

    // mid -> sT; reload sW = Wb (overlaps)
    #pragma unroll
    for (int i = 0; i < 2; i++) {
        float4 m;
        m.x = fmaxf(acc[i][0], 0.f); m.y = fmaxf(acc[i][1], 0.f);
        m.z = fmaxf(acc[i][2], 0.f); m.w = fmaxf(acc[i][3], 0.f);
        *(float4*)&sT[r0 + i][c0] = m;
    }
    for (int i = tid; i < DIM * DIM; i += 512) sW[i] = Wb[i];
    __syncthreads();

    // GEMM2: out = relu(mid @ Wb + Bb)
    {
        float4 bib = *(const float4*)&sBb[c0];
        #pragma unroll
        for (int i = 0; i < 2; i++) {
            acc[i][0] = bib.x; acc[i][1] = bib.y; acc[i][2] = bib.z; acc[i][3] = bib.w;
        }
    }
    #pragma unroll 8
    for (int k = 0; k < DIM; k++) {
        float4 b = *(const float4*)&sW[k * DIM + c0];
        float a0 = sT[r0 + 0][k], a1 = sT[r0 + 1][k];
        acc[0][0] = fmaf(a0, b.x, acc[0][0]); acc[0][1] = fmaf(a0, b.y, acc[0][1]);
        acc[0][2] = fmaf(a0, b.z, acc[0][2]); acc[0][3] = fmaf(a0, b.w, acc[0][3]);
        acc[1][0] = fmaf(a1, b.x, acc[1][0]); acc[1][1] = fmaf(a1, b.y, acc[1][1]);
        acc[1][2] = fmaf(a1, b.z, acc[1][2]); acc[1][3] = fmaf(a1, b.w, acc[1][3]);
    }

    // relu, store bf16, per-thread BN partials (valid rows only)
    float s[4] = {0.f, 0.f, 0.f, 0.f}, q[4] = {0.f, 0.f, 0.f, 0.f};
    #pragma unroll
    for (int i = 0; i < 2; i++) {
        int r = rbase + r0 + i;
        float4 o;
        o.x = fmaxf(acc[i][0], 0.f); o.y = fmaxf(acc[i][1], 0.f);
        o.z = fmaxf(acc[i][2], 0.f); o.w = fmaxf(acc[i][3], 0.f);
        if (r < N) {
            ushort4 ub;
            ub.x = f2bf(o.x); ub.y = f2bf(o.y); ub.z = f2bf(o.z); ub.w = f2bf(o.w);
            *(ushort4*)&hout[(size_t)r * DIM + c0] = ub;
            s[0] += o.x; q[0] += o.x * o.x;
            s[1] += o.y; q[1] += o.y * o.y;
            s[2] += o.z; q[2] += o.z * o.z;
            s[3] += o.w; q[3] += o.w * o.w;
        }
    }
    // reduce over the row-groups within each wave: lanes +16, +32
    #pragma unroll
    for (int j = 0; j < 4; j++) {
        s[j] += __shfl_xor(s[j], 16); s[j] += __shfl_xor(s[j], 32);
        q[j] += __shfl_xor(q[j], 16); q[j] += __shfl_xor(q[j], 32);
    }
    if (lane < 16) {
        #pragma unroll
        for (int j = 0; j < 4; j++) {
            sred[wave][lane][j] = s[j];
            sred[wave][lane][4 + j] = q[j];
        }
    }
    __syncthreads();
    if (tid < DIM) {
        int txx = tid >> 2, j = tid & 3;
        float as = 0.f, aq = 0.f;
        #pragma unroll
        for (int w = 0; w < 8; w++) {
            as += sred[w][txx][j];
            aq += sred[w][txx][4 + j];
        }
        atomicAdd(&stats[tid], as);
        atomicAdd(&stats[DIM + tid], aq);
    }
}

// pool with folded BN3 (affine computed inline from stats3): one wave per graph
// (batch sorted -> binary search range), reads bf16 h3, writes d_out. No atomics.
__global__ void gin_pool(const u16* __restrict__ h, const int* __restrict__ batch,
                         const float* __restrict__ stats, const float* __restrict__ gamma,
                         const float* __restrict__ beta, float invN,
                         void* __restrict__ out, int N, int G,
                         const int* __restrict__ flag) {
    int gw = (blockIdx.x * blockDim.x + threadIdx.x) >> 6;
    int lane = threadIdx.x & 63;
    if (gw >= G) return;
    float m = stats[lane] * invN;
    float var = stats[DIM + lane] * invN - m * m;
    float sc = gamma[lane] * rsqrtf(var + BN_EPS);
    float sh = beta[lane] - sc * m;
    int lo = 0, hi = N;
    while (lo < hi) { int mid = (lo + hi) >> 1; if (batch[mid] < gw) lo = mid + 1; else hi = mid; }
    int s0 = lo;
    hi = N;
    while (lo < hi) { int mid = (lo + hi) >> 1; if (batch[mid] < gw + 1) lo = mid + 1; else hi = mid; }
    int s1 = lo;
    float a0 = 0.f, a1 = 0.f, a2 = 0.f, a3 = 0.f;
    int n = s0;
    for (; n + 3 < s1; n += 4) {
        a0 += bf2f(h[(size_t)n * DIM + lane]);
        a1 += bf2f(h[(size_t)(n + 1) * DIM + lane]);
        a2 += bf2f(h[(size_t)(n + 2) * DIM + lane]);
        a3 += bf2f(h[(size_t)(n + 3) * DIM + lane]);
    }
    for (; n < s1; n++) a0 += bf2f(h[(size_t)n * DIM + lane]);
    float acc = (a0 + a1) + (a2 + a3);
    float v = sc * acc + (float)(s1 - s0) * sh;
    int f = flag[0];
    if (f) ((bf16*)out)[gw * DIM + lane] = __float2bfloat16(v);
    else   ((float*)out)[gw * DIM + lane] = v;
}

extern "C" void kernel_launch(void* const* d_in, const int* in_sizes, int n_in,
                              void* d_out, int out_size, void* d_ws, size_t ws_size,
                              hipStream_t stream) {
    (void)hipGetLastError();  // clear any stale error

    const int N = in_sizes[0] / DIM;   // F_IN == DIM == 64
    const int E = in_sizes[1] / 2;
    const int G = out_size / DIM;
    const size_t ND = (size_t)N * DIM;

    const void* x     = d_in[0];
    const int*  ei    = (const int*)d_in[1];
    const int*  srcp  = ei;
    const int*  dstp  = ei + E;
    const int*  batch = (const int*)d_in[2];

    // bucket shift: start at 8 (250-B mscatter runs); NBUCK <= 2048, W <= MAXW;
    // packed ebuf needs (src << SHIFT) to fit 32 bits.
    int SHIFT = 8;
    while ((((N - 1) >> SHIFT) + 1) > 2048) SHIFT++;
    const int NBUCK = ((N - 1) >> SHIFT) + 1;   // N=100k -> 391
    const int packed_ok = ((unsigned long long)(N - 1) << SHIFT) <= 0xFFFFFFFFull;

    // workspace layout (4-B units from d_ws)
    int*   flag   = (int*)d_ws;                  // [64]
    float* P      = (float*)d_ws + 64;           // [25600] staged f32 params
    int*   bcnt   = (int*)(P + 25600);           // [2048] counts -> bases
    int*   bcur   = bcnt + 2048;                 // [2048] reservation cursors
    float* stats  = (float*)(bcur + 2048);       // [384] = 3 layers x 128
    int*   rowptr = (int*)(stats + 384);         // [N+1]
    int*   adj    = rowptr + (N + 1);            // [E]
    size_t ha4    = ((size_t)(adj - (int*)d_ws) + (size_t)E + 3) & ~(size_t)3;
    u16*   hA     = (u16*)((int*)d_ws + ha4);    // [ND] bf16 (16-B aligned)
    u16*   hB     = hA + ND;                     // [ND] bf16
    u32*   ebuf   = (u32*)hA;                    // [E] aliases h region (CSR build
                                                 // runs BEFORE x-convert)
    size_t need   = (char*)(hB + ND) - (char*)d_ws;
    if (ws_size < need || NBUCK > 2048 || (1 << SHIFT) > MAXW || !packed_ok) {
        hipMemsetAsync(d_out, 0x77, (size_t)out_size * 2, stream);  // ~5e33 marker
        return;
    }

    // param staging pack: per layer {wa, ba, wb, bb, gamma, beta}
    ParamPack pk;
    int off = 0;
    for (int l = 0; l < 3; l++) {
        for (int j = 0; j < 6; j++) {
            int idx = 3 + 6 * l + j;
            pk.p[6 * l + j]   = d_in[idx];
            pk.n[6 * l + j]   = in_sizes[idx];
            pk.off[6 * l + j] = off;
            off += in_sizes[idx];
        }
    }
    float* wa[3], *ba[3], *wb[3], *bb[3], *gm[3], *be[3];
    for (int l = 0; l < 3; l++) {
        float* base = P + l * 8448;
        wa[l] = base;        ba[l] = base + 4096;
        wb[l] = base + 4160; bb[l] = base + 8256;
        gm[l] = base + 8320; be[l] = base + 8384;
    }

    const int TB = 256;
    const int grid_nd4 = (int)((ND / 4 + TB - 1) / TB);
    const int grid_g   = (G * DIM + TB - 1) / TB;
    const int grid_mlp = (N + 63) / 64;
    const int grid_ms  = (E + MS_CHUNK - 1) / MS_CHUNK;
    const float invN   = 1.0f / (float)N;

    // params staged + dtype detect fused (block 0 publishes flag)
    gin_cvt_params<<<18, 256, 0, stream>>>(pk, P, (const unsigned short*)d_in[3],
                                           in_sizes[3], flag);

    // ---- CSR build (once; ebuf aliases h region, so build before x-convert) ----
    gin_zero<<<18, TB, 0, stream>>>((float*)bcnt, 2048 + 2048 + 384);  // bcnt|bcur|stats
    gin_bhist<<<256, 256, 0, stream>>>(dstp, bcnt, E, SHIFT, NBUCK);
    gin_scan2<<<1, 256, 0, stream>>>(bcnt, NBUCK);                     // -> excl. bases
    gin_mscatter<<<grid_ms, 512, 0, stream>>>(srcp, dstp, bcnt, bcur, ebuf, E, SHIFT, NBUCK);
    gin_bfill<<<NBUCK, 256, 0, stream>>>(ebuf, bcnt, rowptr, adj, E, N, SHIFT, NBUCK);

    // x -> bf16 h (after CSR build; hA aliased ebuf)
    GINEncoder_16114717295311_kernel<<<grid_nd4, TB, 0, stream>>>(x, hA, (int)(ND / 4), flag);

    // L1: hA -> hB (identity affine), L2: hB -> hA, L3: hA -> hB (all bf16)
    gin_gmlp<<<grid_mlp, 512, 0, stream>>>(hA, hB, rowptr, adj,
                                           nullptr, nullptr, nullptr,
                                           wa[0], ba[0], wb[0], bb[0],
                                           stats + 0, N, invN);
    gin_gmlp<<<grid_mlp, 512, 0, stream>>>(hB, hA, rowptr, adj,
                                           stats + 0, gm[0], be[0],
                                           wa[1], ba[1], wb[1], bb[1],
                                           stats + 128, N, invN);
    gin_gmlp<<<grid_mlp, 512, 0, stream>>>(hA, hB, rowptr, adj,
                                           stats + 128, gm[1], be[1],
                                           wa[2], ba[2], wb[2], bb[2],
                                           stats + 256, N, invN);

    gin_pool<<<grid_g, TB, 0, stream>>>(hB, batch, stats + 256, gm[2], be[2], invN,
                                        d_out, N, G, flag);

    // "some launch failed" marker: err prints ~1.7e38 (bf16) / 3.4e38 (f32)
    hipError_t e = hipGetLastError();
    if (e != hipSuccess) {
        hipMemsetAsync(d_out, 0x7F, (size_t)out_size * 2, stream);
    }
}

// Round 13
// 513.754 us; speedup vs baseline: 4.0112x; 1.0253x over previous
//
#include <hip/hip_runtime.h>
#include <hip/hip_bf16.h>

typedef __hip_bfloat16 bf16;
typedef unsigned short u16;
typedef unsigned int u32;

#define DIM 64
#define BN_EPS 1e-5f

struct ParamPack {
    const void* p[18];
    int n[18];
    int off[18];
};

// ---- read element i of p as float, interpreting per flag (1=bf16, 0=f32) ----
__device__ __forceinline__ float load_as(const void* p, int i, int isbf16) {
    if (isbf16) {
        unsigned short b = ((const unsigned short*)p)[i];
        unsigned int u = ((unsigned int)b) << 16;
        return __uint_as_float(u);
    }
    return ((const float*)p)[i];
}

__device__ __forceinline__ float bf2f(unsigned short b) {
    unsigned int u = ((unsigned int)b) << 16;
    return __uint_as_float(u);
}

// round-to-nearest-even f32 -> bf16 bits (finite values only)
__device__ __forceinline__ unsigned short f2bf(float f) {
    unsigned int u = __float_as_uint(f);
    unsigned int r = u + 0x7fff + ((u >> 16) & 1);
    return (unsigned short)(r >> 16);
}

// ---- stage all 18 param tensors into f32 workspace; dtype-detect fused in
// (each block re-scans w1a locally -- 8 KB, free; block 0 publishes flag).
// Detect: w1a uniform in +-0.125; bf16 interp of real bf16 data passes ~100%,
// of f32 bits ~55%. ----
__global__ void gin_cvt_params(ParamPack pk, float* __restrict__ out,
                               const unsigned short* __restrict__ w, int wn,
                               int* __restrict__ flag) {
    __shared__ int sc[256];
    int tid = threadIdx.x;
    int cnt = 0;
    for (int i = tid; i < wn; i += 256) {
        unsigned int fb = ((unsigned int)w[i]) << 16;
        float av = fabsf(__uint_as_float(fb));
        if (av <= 0.126f && (av == 0.0f || av >= 1e-8f)) cnt++;
    }
    sc[tid] = cnt;
    __syncthreads();
    for (int s = 128; s > 0; s >>= 1) {
        if (tid < s) sc[tid] += sc[tid + s];
        __syncthreads();
    }
    int f = (sc[0] * 10 >= wn * 9) ? 1 : 0;
    if (blockIdx.x == 0 && tid == 0) flag[0] = f;

    int b = blockIdx.x;
    const void* p = pk.p[b];
    float* o = out + pk.off[b];
    int n = pk.n[b];
    for (int i = tid; i < n; i += 256) o[i] = load_as(p, i, f);
}

// ---- x -> bf16 h, vectorized 4/thread. EARLY-EXITS when input is already
// bf16 (gmlp L1 then reads x directly -- identical layout). ----
__global__ void GINEncoder_16114717295311_kernel(const void* __restrict__ x,
                                                 u16* __restrict__ h, int n4,
                                                 const int* __restrict__ flag) {
    if (flag[0]) return;   // bf16 input: no conversion needed
    int i = blockIdx.x * blockDim.x + threadIdx.x;   // group-of-4 index
    if (i < n4) {
        float4 v = ((const float4*)x)[i];
        ushort4 o;
        o.x = f2bf(v.x); o.y = f2bf(v.y); o.z = f2bf(v.z); o.w = f2bf(v.w);
        ((ushort4*)h)[i] = o;
    }
}

__global__ void gin_zero(float* __restrict__ p, int n) {
    int i = blockIdx.x * blockDim.x + threadIdx.x;
    if (i < n) p[i] = 0.0f;
}

// ======================= CSR build (once; graph reused 3x) =======================
// History: r3 random fill = 17x write amp (107 MB); r4 multi-pass = rescans,
// slower; r5 direct global atomics onto bucket addrs = 431 us contention;
// r10 flat-edge LDS-f32-atomic gather = 639 us (hipcc lowers float atomicAdd
// on LDS to a CAS loop). KEPT structure = r7/r9/r11: LDS-privatized bucket
// histogram + block-local multi-split scatter + per-bucket block-local fill.
// ebuf packed u32 ((src<<SHIFT) | dst-offset) since r12.

// bucket-count histogram, LDS-privatized (one flush atomic per block+bucket)
__global__ void gin_bhist(const int* __restrict__ dst, int* __restrict__ bcnt,
                          int E, int shift, int nbuck) {
    __shared__ int lh[2048];
    int tid = threadIdx.x;
    for (int i = tid; i < nbuck; i += 256) lh[i] = 0;
    __syncthreads();
    int stride = gridDim.x * 256;
    for (int e = blockIdx.x * 256 + tid; e < E; e += stride)
        atomicAdd(&lh[dst[e] >> shift], 1);
    __syncthreads();
    for (int i = tid; i < nbuck; i += 256) {
        int c = lh[i];
        if (c) atomicAdd(&bcnt[i], c);
    }
}

// single block, exclusive scan over up to 2048 ints (in place)
__global__ void gin_scan2(int* __restrict__ part, int NB) {
    __shared__ int lds[256];
    int tid = threadIdx.x;
    int base = tid * 8;
    int a[8];
    int s = 0;
    #pragma unroll
    for (int k = 0; k < 8; k++) {
        a[k] = (base + k < NB) ? part[base + k] : 0;
        s += a[k];
    }
    lds[tid] = s;
    __syncthreads();
    for (int off = 1; off < 256; off <<= 1) {
        int v = (tid >= off) ? lds[tid - off] : 0;
        __syncthreads();
        lds[tid] += v;
        __syncthreads();
    }
    int p = lds[tid] - s;  // exclusive prefix
    #pragma unroll
    for (int k = 0; k < 8; k++) {
        if (base + k < NB) { part[base + k] = p; p += a[k]; }
    }
}

// block-local multi-split scatter: each block takes MS_CHUNK contiguous edges,
// computes per-bucket local positions in LDS, reserves bucket space with ONE
// global atomic per (block,bucket), then writes packed (src<<SHIFT)|off
// bucket-grouped (u32 -- half the bytes of int2).
#define MS_CHUNK 12288
__global__ void gin_mscatter(const int* __restrict__ src, const int* __restrict__ dst,
                             const int* __restrict__ bbase, int* __restrict__ bcur,
                             u32* __restrict__ ebuf, int E, int shift, int nbuck) {
    __shared__ unsigned short spos[MS_CHUNK];  // 24 KB
    __shared__ int lcnt[2048];                 // 8 KB
    __shared__ int lbase[2048];                // 8 KB
    int tid = threadIdx.x;  // 512
    int e0 = blockIdx.x * MS_CHUNK;
    int ecnt = min(MS_CHUNK, E - e0);
    u32 mask = (1u << shift) - 1u;
    for (int i = tid; i < nbuck; i += 512) lcnt[i] = 0;
    __syncthreads();
    for (int i = tid; i < ecnt; i += 512) {
        int b = dst[e0 + i] >> shift;
        spos[i] = (unsigned short)atomicAdd(&lcnt[b], 1);
    }
    __syncthreads();
    for (int i = tid; i < nbuck; i += 512) {
        int c = lcnt[i];
        lbase[i] = c ? (bbase[i] + atomicAdd(&bcur[i], c)) : 0;
    }
    __syncthreads();
    for (int i = tid; i < ecnt; i += 512) {
        int d = dst[e0 + i];
        int b = d >> shift;
        ebuf[lbase[b] + spos[i]] = ((u32)src[e0 + i] << shift) | ((u32)d & mask);
    }
}

// per-bucket CSR fill: block b owns nodes [b<<shift, ...+W) and the contiguous
// ebuf slice [bbase[b], bbase[b+1]). Local deg histogram + local scan in LDS,
// rowptr written directly, adj scattered into a contiguous window.
// NO global atomics (int LDS atomics only -- native, unlike f32).
#define MAXW 2048
__global__ void gin_bfill(const u32* __restrict__ ebuf, const int* __restrict__ bbase,
                          int* __restrict__ rowptr, int* __restrict__ adj,
                          int E, int N, int shift, int nbuck) {
    __shared__ int lcnt[MAXW];
    __shared__ int lptr[MAXW];
    __shared__ int tsum[256];
    int b = blockIdx.x;
    int lo = b << shift;
    int W = min(1 << shift, N - lo);
    int tid = threadIdx.x;  // 256
    int base = bbase[b];
    int end = (b + 1 < nbuck) ? bbase[b + 1] : E;
    int cnt = end - base;
    u32 mask = (1u << shift) - 1u;

    for (int i = tid; i < W; i += 256) lcnt[i] = 0;
    __syncthreads();
    for (int i = tid; i < cnt; i += 256)
        atomicAdd(&lcnt[ebuf[base + i] & mask], 1);
    __syncthreads();

    // exclusive scan of lcnt[0..W): per-thread chunk + Hillis-Steele over totals
    int per = (W + 255) >> 8;
    int i0 = tid * per;
    int s = 0;
    for (int k = 0; k < per; k++) {
        int i = i0 + k;
        if (i < W) { int t = lcnt[i]; lptr[i] = s; s += t; }
    }
    tsum[tid] = s;
    __syncthreads();
    for (int off = 1; off < 256; off <<= 1) {
        int v = (tid >= off) ? tsum[tid - off] : 0;
        __syncthreads();
        tsum[tid] += v;
        __syncthreads();
    }
    int tb = tsum[tid] - s;  // exclusive thread base
    for (int k = 0; k < per; k++) {
        int i = i0 + k;
        if (i < W) {
            int g = base + tb + lptr[i];
            lptr[i] = g;             // global adj base for node lo+i
            rowptr[lo + i] = g;
            lcnt[i] = 0;             // reuse as cursor
        }
    }
    if (b == nbuck - 1 && tid == 0) rowptr[N] = E;
    __syncthreads();

    for (int i = tid; i < cnt; i += 256) {
        u32 e = ebuf[base + i];
        int d = (int)(e & mask);
        int pos = atomicAdd(&lcnt[d], 1);   // LDS int atomic
        adj[lptr[d] + pos] = (int)(e >> shift);
    }
}

// ======================= per-layer fused kernel =======================

// Fused gather + MLP, v8 = r12's v7 (gather FROZEN -- three structures and
// both scaling knobs converged to ~113-125 us; it's the random-read service
// floor) + two epilogue fusions:
//  - L1 reads x DIRECTLY when input is bf16 (xalt + flag; convert skipped).
//  - L3 (pool != nullptr): skip hout store entirely; per-block per-graph
//    partial sums via LDS walk (block's 64 rows are contiguous, batch sorted
//    -> ~2 graphs/block) + ONE global f32 atomicAdd per (graph,ch) per block
//    (~300K atomics onto 32K addresses = ~10-way -- nothing like r5's
//    2050-way pileup). Pool = sc*SUM(h3) + cnt*sh is linear in BN3, so the
//    affine moves to gin_finish.
// 512 thr / 8 waves, LDS ~39 KB -> 4 blocks/CU, 32 waves/CU.
__global__ void gin_gmlp(const u16* __restrict__ hin, u16* __restrict__ hout,
                         const void* __restrict__ xalt,
                         const int* __restrict__ flag,
                         const int* __restrict__ rowptr, const int* __restrict__ adj,
                         const float* __restrict__ pstats, const float* __restrict__ pgamma,
                         const float* __restrict__ pbeta,
                         const float* __restrict__ Wa, const float* __restrict__ Ba,
                         const float* __restrict__ Wb, const float* __restrict__ Bb,
                         float* __restrict__ stats, float* __restrict__ pool,
                         const int* __restrict__ batch, int N, float invN) {
    __shared__ float sW[DIM * DIM];     // 16 KB, Wa then Wb
    __shared__ float sT[64][DIM + 4];   // 17 KB; +4 pad keeps rows 16B-aligned
    __shared__ float sBa[DIM], sBb[DIM], sSS[2 * DIM];
    __shared__ float sred[8][16][8];    // 4 KB
    __shared__ int sBatch[64];

    int tid = threadIdx.x;              // 512
    int lane = tid & 63, wave = tid >> 6;
    int rbase = blockIdx.x * 64;
    const bool dopool = (pool != nullptr);

    const u16* hsrc = hin;
    if (xalt && flag[0]) hsrc = (const u16*)xalt;   // bf16 input: read x directly

    for (int i = tid; i < DIM * DIM; i += 512) sW[i] = Wa[i];
    if (tid < DIM) { sBa[tid] = Ba[tid]; sBb[tid] = Bb[tid]; }
    if (tid >= 64 && tid < 128) {
        int d = tid - 64;
        float sc = 1.f, sh = 0.f;
        if (pstats) {
            float m = pstats[d] * invN;
            float var = pstats[DIM + d] * invN - m * m;
            sc = pgamma[d] * rsqrtf(var + BN_EPS);
            sh = pbeta[d] - sc * m;
        }
        sSS[d] = sc; sSS[DIM + d] = sh;
    }
    if (dopool && tid >= 128 && tid < 192) {
        int rr = tid - 128;
        sBatch[rr] = (rbase + rr < N) ? batch[rbase + rr] : -1;
    }
    __syncthreads();   // sSS/sBatch visible to all waves before gather

    // ---- phase 1: paired-row gather into LDS tile (FROZEN since r9) ----
    {
        int half = lane >> 5;           // 0: even row, 1: odd row
        int c = lane & 31;              // channel-pair index (channels 2c, 2c+1)
        float2 sc = *(const float2*)&sSS[2 * c];
        float2 sh = *(const float2*)&sSS[DIM + 2 * c];
        for (int pi = wave; pi < 32; pi += 8) {
            int rr = 2 * pi + half;
            int row = rbase + rr;
            float v0 = 0.f, v1 = 0.f;
            float degp1 = 0.f;
            if (row < N) {
                int rb = rowptr[row], re = rowptr[row + 1];
                degp1 = (float)(re - rb + 1);
                unsigned int u = *(const unsigned int*)&hsrc[(size_t)row * DIM + 2 * c];
                v0 = bf2f((unsigned short)u);
                v1 = bf2f((unsigned short)(u >> 16));
                int j = rb;
                for (; j + 8 <= re; j += 8) {
                    int s0 = adj[j], s1 = adj[j + 1], s2 = adj[j + 2], s3 = adj[j + 3];
                    int s4 = adj[j + 4], s5 = adj[j + 5], s6 = adj[j + 6], s7 = adj[j + 7];
                    unsigned int u0 = *(const unsigned int*)&hsrc[(size_t)s0 * DIM + 2 * c];
                    unsigned int u1 = *(const unsigned int*)&hsrc[(size_t)s1 * DIM + 2 * c];
                    unsigned int u2 = *(const unsigned int*)&hsrc[(size_t)s2 * DIM + 2 * c];
                    unsigned int u3 = *(const unsigned int*)&hsrc[(size_t)s3 * DIM + 2 * c];
                    unsigned int u4 = *(const unsigned int*)&hsrc[(size_t)s4 * DIM + 2 * c];
                    unsigned int u5 = *(const unsigned int*)&hsrc[(size_t)s5 * DIM + 2 * c];
                    unsigned int u6 = *(const unsigned int*)&hsrc[(size_t)s6 * DIM + 2 * c];
                    unsigned int u7 = *(const unsigned int*)&hsrc[(size_t)s7 * DIM + 2 * c];
                    v0 += ((bf2f((u16)u0) + bf2f((u16)u1)) + (bf2f((u16)u2) + bf2f((u16)u3)))
                        + ((bf2f((u16)u4) + bf2f((u16)u5)) + (bf2f((u16)u6) + bf2f((u16)u7)));
                    v1 += ((bf2f((u16)(u0 >> 16)) + bf2f((u16)(u1 >> 16)))
                         + (bf2f((u16)(u2 >> 16)) + bf2f((u16)(u3 >> 16))))
                        + ((bf2f((u16)(u4 >> 16)) + bf2f((u16)(u5 >> 16)))
                         + (bf2f((u16)(u6 >> 16)) + bf2f((u16)(u7 >> 16))));
                }
                for (; j < re; j++) {
                    int s = adj[j];
                    unsigned int uu = *(const unsigned int*)&hsrc[(size_t)s * DIM + 2 * c];
                    v0 += bf2f((u16)uu);
                    v1 += bf2f((u16)(uu >> 16));
                }
            }
            float2 o;
            o.x = sc.x * v0 + degp1 * sh.x;
            o.y = sc.y * v1 + degp1 * sh.y;
            *(float2*)&sT[rr][2 * c] = o;
        }
    }
    __syncthreads();

    // ---- phase 2: GEMM pair, each thread owns rows r0..r0+1 x cols c0..c0+3
    int tx = tid & 15, ty = tid >> 4;   // ty 0..31
    int c0 = tx * 4;
    int r0 = ty * 2;
    float acc[2][4];

    // GEMM1: mid = relu(tile @ Wa + Ba)
    {
        float4 bia = *(const float4*)&sBa[c0];
        #pragma unroll
        for (int i = 0; i < 2; i++) {
            acc[i][0] = bia.x; acc[i][1] = bia.y; acc[i][2] = bia.z; acc[i][3] = bia.w;
        }
    }
    #pragma unroll 8
    for (int k = 0; k < DIM; k++) {
        float4 b = *(const float4*)&sW[k * DIM + c0];
        float a0 = sT[r0 + 0][k], a1 = sT[r0 + 1][k];
        acc[0][0] = fmaf(a0, b.x, acc[0][0]); acc[0][1] = fmaf(a0, b.y, acc[0][1]);
        acc[0][2] = fmaf(a0, b.z, acc[0][2]); acc[0][3] = fmaf(a0, b.w, acc[0][3]);
        acc[1][0] = fmaf(a1, b.x, acc[1][0]); acc[1][1] = fmaf(a1, b.y, acc[1][1]);
        acc[1][2] = fmaf(a1, b.z, acc[1][2]); acc[1][3] = fmaf(a1, b.w, acc[1][3]);
    }
    __syncthreads();  // all GEMM1 reads of sT and sW done

    // mid -> sT; reload sW = Wb (overlaps)
    #pragma unroll
    for (int i = 0; i < 2; i++) {
        float4 m;
        m.x = fmaxf(acc[i][0], 0.f); m.y = fmaxf(acc[i][1], 0.f);
        m.z = fmaxf(acc[i][2], 0.f); m.w = fmaxf(acc[i][3], 0.f);
        *(float4*)&sT[r0 + i][c0] = m;
    }
    for (int i = tid; i < DIM * DIM; i += 512) sW[i] = Wb[i];
    __syncthreads();

    // GEMM2: out = relu(mid @ Wb + Bb)
    {
        float4 bib = *(const float4*)&sBb[c0];
        #pragma unroll
        for (int i = 0; i < 2; i++) {
            acc[i][0] = bib.x; acc[i][1] = bib.y; acc[i][2] = bib.z; acc[i][3] = bib.w;
        }
    }
    #pragma unroll 8
    for (int k = 0; k < DIM; k++) {
        float4 b = *(const float4*)&sW[k * DIM + c0];
        float a0 = sT[r0 + 0][k], a1 = sT[r0 + 1][k];
        acc[0][0] = fmaf(a0, b.x, acc[0][0]); acc[0][1] = fmaf(a0, b.y, acc[0][1]);
        acc[0][2] = fmaf(a0, b.z, acc[0][2]); acc[0][3] = fmaf(a0, b.w, acc[0][3]);
        acc[1][0] = fmaf(a1, b.x, acc[1][0]); acc[1][1] = fmaf(a1, b.y, acc[1][1]);
        acc[1][2] = fmaf(a1, b.z, acc[1][2]); acc[1][3] = fmaf(a1, b.w, acc[1][3]);
    }
    __syncthreads();  // all GEMM2 reads of sT done (sT reused for pool walk)

    // relu; store bf16 (non-pool layers) or stage into sT (pool layer);
    // per-thread BN partials (valid rows only)
    float s[4] = {0.f, 0.f, 0.f, 0.f}, q[4] = {0.f, 0.f, 0.f, 0.f};
    #pragma unroll
    for (int i = 0; i < 2; i++) {
        int r = rbase + r0 + i;
        float4 o;
        o.x = fmaxf(acc[i][0], 0.f); o.y = fmaxf(acc[i][1], 0.f);
        o.z = fmaxf(acc[i][2], 0.f); o.w = fmaxf(acc[i][3], 0.f);
        if (r < N) {
            if (dopool) {
                *(float4*)&sT[r0 + i][c0] = o;
            } else {
                ushort4 ub;
                ub.x = f2bf(o.x); ub.y = f2bf(o.y); ub.z = f2bf(o.z); ub.w = f2bf(o.w);
                *(ushort4*)&hout[(size_t)r * DIM + c0] = ub;
            }
            s[0] += o.x; q[0] += o.x * o.x;
            s[1] += o.y; q[1] += o.y * o.y;
            s[2] += o.z; q[2] += o.z * o.z;
            s[3] += o.w; q[3] += o.w * o.w;
        }
    }
    // reduce over the row-groups within each wave: lanes +16, +32
    #pragma unroll
    for (int j = 0; j < 4; j++) {
        s[j] += __shfl_xor(s[j], 16); s[j] += __shfl_xor(s[j], 32);
        q[j] += __shfl_xor(q[j], 16); q[j] += __shfl_xor(q[j], 32);
    }
    if (lane < 16) {
        #pragma unroll
        for (int j = 0; j < 4; j++) {
            sred[wave][lane][j] = s[j];
            sred[wave][lane][4 + j] = q[j];
        }
    }
    __syncthreads();
    if (tid < DIM) {
        int txx = tid >> 2, j = tid & 3;
        float as = 0.f, aq = 0.f;
        #pragma unroll
        for (int w = 0; w < 8; w++) {
            as += sred[w][txx][j];
            aq += sred[w][txx][4 + j];
        }
        atomicAdd(&stats[tid], as);
        atomicAdd(&stats[DIM + tid], aq);
    }
    // pool walk: 64 channel-threads, serial over the block's 64 contiguous
    // rows, flush one atomicAdd per (graph, channel) run (~2 graphs/block)
    if (dopool && tid < DIM) {
        int ch = tid;
        float accp = 0.f;
        int g = sBatch[0];
        for (int rr = 0; rr < 64; rr++) {
            int gb = sBatch[rr];
            if (gb < 0) break;
            if (gb != g) {
                atomicAdd(&pool[(size_t)g * DIM + ch], accp);
                accp = 0.f; g = gb;
            }
            accp += sT[rr][ch];
        }
        atomicAdd(&pool[(size_t)g * DIM + ch], accp);
    }
}

// finalize: out[g] = sc * pool[g] + cnt_g * sh (BN3 affine folded through the
// linear pool). cnt_g via binary search (batch sorted); no h reads. One wave
// per graph.
__global__ void gin_finish(const float* __restrict__ pool, const int* __restrict__ batch,
                           const float* __restrict__ stats, const float* __restrict__ gamma,
                           const float* __restrict__ beta, float invN,
                           void* __restrict__ out, int N, int G,
                           const int* __restrict__ flag) {
    int gw = (blockIdx.x * blockDim.x + threadIdx.x) >> 6;
    int lane = threadIdx.x & 63;
    if (gw >= G) return;
    float m = stats[lane] * invN;
    float var = stats[DIM + lane] * invN - m * m;
    float sc = gamma[lane] * rsqrtf(var + BN_EPS);
    float sh = beta[lane] - sc * m;
    int lo = 0, hi = N;
    while (lo < hi) { int mid = (lo + hi) >> 1; if (batch[mid] < gw) lo = mid + 1; else hi = mid; }
    int s0 = lo;
    hi = N;
    while (lo < hi) { int mid = (lo + hi) >> 1; if (batch[mid] < gw + 1) lo = mid + 1; else hi = mid; }
    int cnt = lo - s0;
    float v = sc * pool[(size_t)gw * DIM + lane] + (float)cnt * sh;
    int f = flag[0];
    if (f) ((bf16*)out)[gw * DIM + lane] = __float2bfloat16(v);
    else   ((float*)out)[gw * DIM + lane] = v;
}

extern "C" void kernel_launch(void* const* d_in, const int* in_sizes, int n_in,
                              void* d_out, int out_size, void* d_ws, size_t ws_size,
                              hipStream_t stream) {
    (void)hipGetLastError();  // clear any stale error

    const int N = in_sizes[0] / DIM;   // F_IN == DIM == 64
    const int E = in_sizes[1] / 2;
    const int G = out_size / DIM;
    const size_t ND = (size_t)N * DIM;

    const void* x     = d_in[0];
    const int*  ei    = (const int*)d_in[1];
    const int*  srcp  = ei;
    const int*  dstp  = ei + E;
    const int*  batch = (const int*)d_in[2];

    // bucket shift: start at 8 (250-B mscatter runs); NBUCK <= 2048, W <= MAXW;
    // packed ebuf needs (src << SHIFT) to fit 32 bits.
    int SHIFT = 8;
    while ((((N - 1) >> SHIFT) + 1) > 2048) SHIFT++;
    const int NBUCK = ((N - 1) >> SHIFT) + 1;   // N=100k -> 391
    const int packed_ok = ((unsigned long long)(N - 1) << SHIFT) <= 0xFFFFFFFFull;

    // workspace layout (4-B units from d_ws)
    int*   flag   = (int*)d_ws;                  // [64]
    float* P      = (float*)d_ws + 64;           // [25600] staged f32 params
    int*   bcnt   = (int*)(P + 25600);           // [2048] counts -> bases
    int*   bcur   = bcnt + 2048;                 // [2048] reservation cursors
    float* stats  = (float*)(bcur + 2048);       // [384] = 3 layers x 128
    float* pool   = stats + 384;                 // [G*64] f32 graph sums
    int*   rowptr = (int*)(pool + (size_t)G * DIM);  // [N+1]
    int*   adj    = rowptr + (N + 1);            // [E]
    size_t ha4    = ((size_t)(adj - (int*)d_ws) + (size_t)E + 3) & ~(size_t)3;
    u16*   hA     = (u16*)((int*)d_ws + ha4);    // [ND] bf16 (16-B aligned)
    u16*   hB     = hA + ND;                     // [ND] bf16
    u32*   ebuf   = (u32*)hA;                    // [E] aliases h region (CSR build
                                                 // runs BEFORE x-convert)
    size_t need   = (char*)(hB + ND) - (char*)d_ws;
    if (ws_size < need || NBUCK > 2048 || (1 << SHIFT) > MAXW || !packed_ok) {
        hipMemsetAsync(d_out, 0x77, (size_t)out_size * 2, stream);  // ~5e33 marker
        return;
    }

    // param staging pack: per layer {wa, ba, wb, bb, gamma, beta}
    ParamPack pk;
    int off = 0;
    for (int l = 0; l < 3; l++) {
        for (int j = 0; j < 6; j++) {
            int idx = 3 + 6 * l + j;
            pk.p[6 * l + j]   = d_in[idx];
            pk.n[6 * l + j]   = in_sizes[idx];
            pk.off[6 * l + j] = off;
            off += in_sizes[idx];
        }
    }
    float* wa[3], *ba[3], *wb[3], *bb[3], *gm[3], *be[3];
    for (int l = 0; l < 3; l++) {
        float* base = P + l * 8448;
        wa[l] = base;        ba[l] = base + 4096;
        wb[l] = base + 4160; bb[l] = base + 8256;
        gm[l] = base + 8320; be[l] = base + 8384;
    }

    const int TB = 256;
    const int grid_nd4 = (int)((ND / 4 + TB - 1) / TB);
    const int grid_g   = (G * DIM + TB - 1) / TB;
    const int grid_mlp = (N + 63) / 64;
    const int grid_ms  = (E + MS_CHUNK - 1) / MS_CHUNK;
    const float invN   = 1.0f / (float)N;
    const int nzero    = 2048 + 2048 + 384 + G * DIM;   // bcnt|bcur|stats|pool

    // params staged + dtype detect fused (block 0 publishes flag)
    gin_cvt_params<<<18, 256, 0, stream>>>(pk, P, (const unsigned short*)d_in[3],
                                           in_sizes[3], flag);

    // ---- CSR build (once; ebuf aliases h region, so build before x-convert) ----
    gin_zero<<<(nzero + TB - 1) / TB, TB, 0, stream>>>((float*)bcnt, nzero);
    gin_bhist<<<256, 256, 0, stream>>>(dstp, bcnt, E, SHIFT, NBUCK);
    gin_scan2<<<1, 256, 0, stream>>>(bcnt, NBUCK);                     // -> excl. bases
    gin_mscatter<<<grid_ms, 512, 0, stream>>>(srcp, dstp, bcnt, bcur, ebuf, E, SHIFT, NBUCK);
    gin_bfill<<<NBUCK, 256, 0, stream>>>(ebuf, bcnt, rowptr, adj, E, N, SHIFT, NBUCK);

    // x -> bf16 h (no-op when input already bf16; L1 then reads x directly)
    GINEncoder_16114717295311_kernel<<<grid_nd4, TB, 0, stream>>>(x, hA, (int)(ND / 4), flag);

    // L1: x/hA -> hB (identity affine), L2: hB -> hA, L3: hA -> pool (no hout)
    gin_gmlp<<<grid_mlp, 512, 0, stream>>>(hA, hB, x, flag, rowptr, adj,
                                           nullptr, nullptr, nullptr,
                                           wa[0], ba[0], wb[0], bb[0],
                                           stats + 0, nullptr, nullptr, N, invN);
    gin_gmlp<<<grid_mlp, 512, 0, stream>>>(hB, hA, nullptr, flag, rowptr, adj,
                                           stats + 0, gm[0], be[0],
                                           wa[1], ba[1], wb[1], bb[1],
                                           stats + 128, nullptr, nullptr, N, invN);
    gin_gmlp<<<grid_mlp, 512, 0, stream>>>(hA, hB, nullptr, flag, rowptr, adj,
                                           stats + 128, gm[1], be[1],
                                           wa[2], ba[2], wb[2], bb[2],
                                           stats + 256, pool, batch, N, invN);

    gin_finish<<<grid_g, TB, 0, stream>>>(pool, batch, stats + 256, gm[2], be[2], invN,
                                          d_out, N, G, flag);

    // "some launch failed" marker: err prints ~1.7e38 (bf16) / 3.4e38 (f32)
    hipError_t e = hipGetLastError();
    if (e != hipSuccess) {
        hipMemsetAsync(d_out, 0x7F, (size_t)out_size * 2, stream);
    }
}

// Round 14
// 431.476 us; speedup vs baseline: 4.7761x; 1.1907x over previous
//
#include <hip/hip_runtime.h>
#include <hip/hip_bf16.h>

typedef __hip_bfloat16 bf16;
typedef unsigned short u16;
typedef unsigned int u32;

#define DIM 64
#define BN_EPS 1e-5f

struct ParamPack {
    const void* p[18];
    int n[18];
    int off[18];
};

// ---- read element i of p as float, interpreting per flag (1=bf16, 0=f32) ----
__device__ __forceinline__ float load_as(const void* p, int i, int isbf16) {
    if (isbf16) {
        unsigned short b = ((const unsigned short*)p)[i];
        unsigned int u = ((unsigned int)b) << 16;
        return __uint_as_float(u);
    }
    return ((const float*)p)[i];
}

__device__ __forceinline__ float bf2f(unsigned short b) {
    unsigned int u = ((unsigned int)b) << 16;
    return __uint_as_float(u);
}

// round-to-nearest-even f32 -> bf16 bits (finite values only)
__device__ __forceinline__ unsigned short f2bf(float f) {
    unsigned int u = __float_as_uint(f);
    unsigned int r = u + 0x7fff + ((u >> 16) & 1);
    return (unsigned short)(r >> 16);
}

// ---- stage all 18 param tensors into f32 workspace; dtype-detect fused in
// (each block re-scans w1a locally -- 8 KB, free; block 0 publishes flag).
// Detect: w1a uniform in +-0.125; bf16 interp of real bf16 data passes ~100%,
// of f32 bits ~55%. ----
__global__ void gin_cvt_params(ParamPack pk, float* __restrict__ out,
                               const unsigned short* __restrict__ w, int wn,
                               int* __restrict__ flag) {
    __shared__ int sc[256];
    int tid = threadIdx.x;
    int cnt = 0;
    for (int i = tid; i < wn; i += 256) {
        unsigned int fb = ((unsigned int)w[i]) << 16;
        float av = fabsf(__uint_as_float(fb));
        if (av <= 0.126f && (av == 0.0f || av >= 1e-8f)) cnt++;
    }
    sc[tid] = cnt;
    __syncthreads();
    for (int s = 128; s > 0; s >>= 1) {
        if (tid < s) sc[tid] += sc[tid + s];
        __syncthreads();
    }
    int f = (sc[0] * 10 >= wn * 9) ? 1 : 0;
    if (blockIdx.x == 0 && tid == 0) flag[0] = f;

    int b = blockIdx.x;
    const void* p = pk.p[b];
    float* o = out + pk.off[b];
    int n = pk.n[b];
    for (int i = tid; i < n; i += 256) o[i] = load_as(p, i, f);
}

// ---- x -> bf16 h, vectorized 4/thread. EARLY-EXITS when input is already
// bf16 (gmlp L1 then reads x directly -- identical layout). ----
__global__ void GINEncoder_16114717295311_kernel(const void* __restrict__ x,
                                                 u16* __restrict__ h, int n4,
                                                 const int* __restrict__ flag) {
    if (flag[0]) return;   // bf16 input: no conversion needed
    int i = blockIdx.x * blockDim.x + threadIdx.x;   // group-of-4 index
    if (i < n4) {
        float4 v = ((const float4*)x)[i];
        ushort4 o;
        o.x = f2bf(v.x); o.y = f2bf(v.y); o.z = f2bf(v.z); o.w = f2bf(v.w);
        ((ushort4*)h)[i] = o;
    }
}

__global__ void gin_zero(float* __restrict__ p, int n) {
    int i = blockIdx.x * blockDim.x + threadIdx.x;
    if (i < n) p[i] = 0.0f;
}

// ======================= CSR build (once; graph reused 3x) =======================
// History: r3 random fill = 17x write amp (107 MB); r4 multi-pass = rescans,
// slower; r5 direct global atomics onto bucket addrs = 431 us contention;
// r10 flat-edge LDS-f32-atomic gather = 639 us (hipcc lowers float atomicAdd
// on LDS to a CAS loop). KEPT structure = r7/r9/r11: LDS-privatized bucket
// histogram + block-local multi-split scatter + per-bucket block-local fill.
// ebuf packed u32 ((src<<SHIFT) | dst-offset) since r12.

// bucket-count histogram, LDS-privatized (one flush atomic per block+bucket)
__global__ void gin_bhist(const int* __restrict__ dst, int* __restrict__ bcnt,
                          int E, int shift, int nbuck) {
    __shared__ int lh[2048];
    int tid = threadIdx.x;
    for (int i = tid; i < nbuck; i += 256) lh[i] = 0;
    __syncthreads();
    int stride = gridDim.x * 256;
    for (int e = blockIdx.x * 256 + tid; e < E; e += stride)
        atomicAdd(&lh[dst[e] >> shift], 1);
    __syncthreads();
    for (int i = tid; i < nbuck; i += 256) {
        int c = lh[i];
        if (c) atomicAdd(&bcnt[i], c);
    }
}

// single block, exclusive scan over up to 2048 ints (in place)
__global__ void gin_scan2(int* __restrict__ part, int NB) {
    __shared__ int lds[256];
    int tid = threadIdx.x;
    int base = tid * 8;
    int a[8];
    int s = 0;
    #pragma unroll
    for (int k = 0; k < 8; k++) {
        a[k] = (base + k < NB) ? part[base + k] : 0;
        s += a[k];
    }
    lds[tid] = s;
    __syncthreads();
    for (int off = 1; off < 256; off <<= 1) {
        int v = (tid >= off) ? lds[tid - off] : 0;
        __syncthreads();
        lds[tid] += v;
        __syncthreads();
    }
    int p = lds[tid] - s;  // exclusive prefix
    #pragma unroll
    for (int k = 0; k < 8; k++) {
        if (base + k < NB) { part[base + k] = p; p += a[k]; }
    }
}

// block-local multi-split scatter: each block takes MS_CHUNK contiguous edges,
// computes per-bucket local positions in LDS, reserves bucket space with ONE
// global atomic per (block,bucket), then writes packed (src<<SHIFT)|off
// bucket-grouped (u32 -- half the bytes of int2).
#define MS_CHUNK 12288
__global__ void gin_mscatter(const int* __restrict__ src, const int* __restrict__ dst,
                             const int* __restrict__ bbase, int* __restrict__ bcur,
                             u32* __restrict__ ebuf, int E, int shift, int nbuck) {
    __shared__ unsigned short spos[MS_CHUNK];  // 24 KB
    __shared__ int lcnt[2048];                 // 8 KB
    __shared__ int lbase[2048];                // 8 KB
    int tid = threadIdx.x;  // 512
    int e0 = blockIdx.x * MS_CHUNK;
    int ecnt = min(MS_CHUNK, E - e0);
    u32 mask = (1u << shift) - 1u;
    for (int i = tid; i < nbuck; i += 512) lcnt[i] = 0;
    __syncthreads();
    for (int i = tid; i < ecnt; i += 512) {
        int b = dst[e0 + i] >> shift;
        spos[i] = (unsigned short)atomicAdd(&lcnt[b], 1);
    }
    __syncthreads();
    for (int i = tid; i < nbuck; i += 512) {
        int c = lcnt[i];
        lbase[i] = c ? (bbase[i] + atomicAdd(&bcur[i], c)) : 0;
    }
    __syncthreads();
    for (int i = tid; i < ecnt; i += 512) {
        int d = dst[e0 + i];
        int b = d >> shift;
        ebuf[lbase[b] + spos[i]] = ((u32)src[e0 + i] << shift) | ((u32)d & mask);
    }
}

// per-bucket CSR fill: block b owns nodes [b<<shift, ...+W) and the contiguous
// ebuf slice [bbase[b], bbase[b+1]). Local deg histogram + local scan in LDS,
// rowptr written directly, adj scattered into a contiguous window.
// NO global atomics (int LDS atomics only -- native, unlike f32).
#define MAXW 2048
__global__ void gin_bfill(const u32* __restrict__ ebuf, const int* __restrict__ bbase,
                          int* __restrict__ rowptr, int* __restrict__ adj,
                          int E, int N, int shift, int nbuck) {
    __shared__ int lcnt[MAXW];
    __shared__ int lptr[MAXW];
    __shared__ int tsum[256];
    int b = blockIdx.x;
    int lo = b << shift;
    int W = min(1 << shift, N - lo);
    int tid = threadIdx.x;  // 256
    int base = bbase[b];
    int end = (b + 1 < nbuck) ? bbase[b + 1] : E;
    int cnt = end - base;
    u32 mask = (1u << shift) - 1u;

    for (int i = tid; i < W; i += 256) lcnt[i] = 0;
    __syncthreads();
    for (int i = tid; i < cnt; i += 256)
        atomicAdd(&lcnt[ebuf[base + i] & mask], 1);
    __syncthreads();

    // exclusive scan of lcnt[0..W): per-thread chunk + Hillis-Steele over totals
    int per = (W + 255) >> 8;
    int i0 = tid * per;
    int s = 0;
    for (int k = 0; k < per; k++) {
        int i = i0 + k;
        if (i < W) { int t = lcnt[i]; lptr[i] = s; s += t; }
    }
    tsum[tid] = s;
    __syncthreads();
    for (int off = 1; off < 256; off <<= 1) {
        int v = (tid >= off) ? tsum[tid - off] : 0;
        __syncthreads();
        tsum[tid] += v;
        __syncthreads();
    }
    int tb = tsum[tid] - s;  // exclusive thread base
    for (int k = 0; k < per; k++) {
        int i = i0 + k;
        if (i < W) {
            int g = base + tb + lptr[i];
            lptr[i] = g;             // global adj base for node lo+i
            rowptr[lo + i] = g;
            lcnt[i] = 0;             // reuse as cursor
        }
    }
    if (b == nbuck - 1 && tid == 0) rowptr[N] = E;
    __syncthreads();

    for (int i = tid; i < cnt; i += 256) {
        u32 e = ebuf[base + i];
        int d = (int)(e & mask);
        int pos = atomicAdd(&lcnt[d], 1);   // LDS int atomic
        adj[lptr[d] + pos] = (int)(e >> shift);
    }
}

// ======================= per-layer fused kernel =======================

// Fused gather + MLP, v9 = r13's v8 with the gather's per-wave ILP doubled:
// TWO row-pairs interleaved per lane, branch-free. r9's diagnosis was
// dependency-chain boundedness (adj -> 8 h-loads -> sum, serial per row);
// r10 attacked it via flat edges and died on an ORTHOGONAL issue (LDS f32
// atomicAdd = CAS loop). This keeps the row-serial accumulation (registers,
// no atomics) but processes rows rrA and rrA+16 concurrently:
//   per iteration: 8 adj(A) + 8 adj(B) + 8 h(A) + 8 h(B) loads, all
//   unconditional (adj index clamped to [0, re-1] -- memory-safe inside the
//   workspace; dead contributions zeroed by ONE v_cndmask per u32, which
//   zeroes both bf16 channels). Ceil-batches replace the serial tail loop
//   (clamp-tail loads hit the just-fetched line = L2-hit).
// ~2x outstanding loads/wave. VGPR target <= 64 (8 waves/SIMD budget); watch
// VGPR_Count/Occupancy -- if > 64, occupancy drops to 3 blocks/CU.
// Epilogues unchanged: L1 reads x directly when bf16; L3 pools in-block.
__global__ void gin_gmlp(const u16* __restrict__ hin, u16* __restrict__ hout,
                         const void* __restrict__ xalt,
                         const int* __restrict__ flag,
                         const int* __restrict__ rowptr, const int* __restrict__ adj,
                         const float* __restrict__ pstats, const float* __restrict__ pgamma,
                         const float* __restrict__ pbeta,
                         const float* __restrict__ Wa, const float* __restrict__ Ba,
                         const float* __restrict__ Wb, const float* __restrict__ Bb,
                         float* __restrict__ stats, float* __restrict__ pool,
                         const int* __restrict__ batch, int N, float invN) {
    __shared__ float sW[DIM * DIM];     // 16 KB, Wa then Wb
    __shared__ float sT[64][DIM + 4];   // 17 KB; +4 pad keeps rows 16B-aligned
    __shared__ float sBa[DIM], sBb[DIM], sSS[2 * DIM];
    __shared__ float sred[8][16][8];    // 4 KB
    __shared__ int sBatch[64];

    int tid = threadIdx.x;              // 512
    int lane = tid & 63, wave = tid >> 6;
    int rbase = blockIdx.x * 64;
    const bool dopool = (pool != nullptr);

    const u16* hsrc = hin;
    if (xalt && flag[0]) hsrc = (const u16*)xalt;   // bf16 input: read x directly

    for (int i = tid; i < DIM * DIM; i += 512) sW[i] = Wa[i];
    if (tid < DIM) { sBa[tid] = Ba[tid]; sBb[tid] = Bb[tid]; }
    if (tid >= 64 && tid < 128) {
        int d = tid - 64;
        float sc = 1.f, sh = 0.f;
        if (pstats) {
            float m = pstats[d] * invN;
            float var = pstats[DIM + d] * invN - m * m;
            sc = pgamma[d] * rsqrtf(var + BN_EPS);
            sh = pbeta[d] - sc * m;
        }
        sSS[d] = sc; sSS[DIM + d] = sh;
    }
    if (dopool && tid >= 128 && tid < 192) {
        int rr = tid - 128;
        sBatch[rr] = (rbase + rr < N) ? batch[rbase + rr] : -1;
    }
    __syncthreads();   // sSS/sBatch visible to all waves before gather

    // ---- phase 1: paired-row gather, 2 row-pairs interleaved per lane ----
    {
        int half = lane >> 5;           // 0: even row, 1: odd row
        int c = lane & 31;              // channel-pair index (channels 2c, 2c+1)
        float2 scv = *(const float2*)&sSS[2 * c];
        float2 shv = *(const float2*)&sSS[DIM + 2 * c];
        const u16* hb = hsrc + 2 * c;   // per-lane channel base
        #pragma unroll
        for (int base = 0; base < 32; base += 16) {
            int rrA = 2 * (base + wave) + half;   // rows rrA and rrA+16
            int rrB = rrA + 16;
            int rowA = rbase + rrA, rowB = rbase + rrB;
            float v0A = 0.f, v1A = 0.f, v0B = 0.f, v1B = 0.f;
            float dpA = 0.f, dpB = 0.f;
            int jA = 0, reA = 0, jB = 0, reB = 0;
            if (rowA < N) {
                jA = rowptr[rowA]; reA = rowptr[rowA + 1];
                dpA = (float)(reA - jA + 1);
                u32 u = *(const u32*)&hb[(size_t)rowA * DIM];
                v0A = bf2f((u16)u); v1A = bf2f((u16)(u >> 16));
            }
            if (rowB < N) {
                jB = rowptr[rowB]; reB = rowptr[rowB + 1];
                dpB = (float)(reB - jB + 1);
                u32 u = *(const u32*)&hb[(size_t)rowB * DIM];
                v0B = bf2f((u16)u); v1B = bf2f((u16)(u >> 16));
            }
            int nA = (reA - jA + 7) >> 3;   // ceil batches (no tail loop)
            int nB = (reB - jB + 7) >> 3;
            int nmax = max(nA, nB);
            int eA = max(reA - 1, 0);       // clamp targets (memory-safe)
            int eB = max(reB - 1, 0);
            for (int t = 0; t < nmax; t++) {
                int sA[8], sB[8];
                #pragma unroll
                for (int k = 0; k < 8; k++) sA[k] = adj[min(jA + k, eA)];
                #pragma unroll
                for (int k = 0; k < 8; k++) sB[k] = adj[min(jB + k, eB)];
                u32 uA[8], uB[8];
                #pragma unroll
                for (int k = 0; k < 8; k++) uA[k] = *(const u32*)&hb[(size_t)sA[k] * DIM];
                #pragma unroll
                for (int k = 0; k < 8; k++) uB[k] = *(const u32*)&hb[(size_t)sB[k] * DIM];
                #pragma unroll
                for (int k = 0; k < 8; k++) {
                    u32 ua = (jA + k < reA) ? uA[k] : 0u;   // 0 -> both bf16 = 0
                    v0A += bf2f((u16)ua); v1A += bf2f((u16)(ua >> 16));
                    u32 ub = (jB + k < reB) ? uB[k] : 0u;
                    v0B += bf2f((u16)ub); v1B += bf2f((u16)(ub >> 16));
                }
                jA += 8; jB += 8;
            }
            float2 oA, oB;
            oA.x = scv.x * v0A + dpA * shv.x;
            oA.y = scv.y * v1A + dpA * shv.y;
            oB.x = scv.x * v0B + dpB * shv.x;
            oB.y = scv.y * v1B + dpB * shv.y;
            *(float2*)&sT[rrA][2 * c] = oA;
            *(float2*)&sT[rrB][2 * c] = oB;
        }
    }
    __syncthreads();

    // ---- phase 2: GEMM pair, each thread owns rows r0..r0+1 x cols c0..c0+3
    int tx = tid & 15, ty = tid >> 4;   // ty 0..31
    int c0 = tx * 4;
    int r0 = ty * 2;
    float acc[2][4];

    // GEMM1: mid = relu(tile @ Wa + Ba)
    {
        float4 bia = *(const float4*)&sBa[c0];
        #pragma unroll
        for (int i = 0; i < 2; i++) {
            acc[i][0] = bia.x; acc[i][1] = bia.y; acc[i][2] = bia.z; acc[i][3] = bia.w;
        }
    }
    #pragma unroll 8
    for (int k = 0; k < DIM; k++) {
        float4 b = *(const float4*)&sW[k * DIM + c0];
        float a0 = sT[r0 + 0][k], a1 = sT[r0 + 1][k];
        acc[0][0] = fmaf(a0, b.x, acc[0][0]); acc[0][1] = fmaf(a0, b.y, acc[0][1]);
        acc[0][2] = fmaf(a0, b.z, acc[0][2]); acc[0][3] = fmaf(a0, b.w, acc[0][3]);
        acc[1][0] = fmaf(a1, b.x, acc[1][0]); acc[1][1] = fmaf(a1, b.y, acc[1][1]);
        acc[1][2] = fmaf(a1, b.z, acc[1][2]); acc[1][3] = fmaf(a1, b.w, acc[1][3]);
    }
    __syncthreads();  // all GEMM1 reads of sT and sW done

    // mid -> sT; reload sW = Wb (overlaps)
    #pragma unroll
    for (int i = 0; i < 2; i++) {
        float4 m;
        m.x = fmaxf(acc[i][0], 0.f); m.y = fmaxf(acc[i][1], 0.f);
        m.z = fmaxf(acc[i][2], 0.f); m.w = fmaxf(acc[i][3], 0.f);
        *(float4*)&sT[r0 + i][c0] = m;
    }
    for (int i = tid; i < DIM * DIM; i += 512) sW[i] = Wb[i];
    __syncthreads();

    // GEMM2: out = relu(mid @ Wb + Bb)
    {
        float4 bib = *(const float4*)&sBb[c0];
        #pragma unroll
        for (int i = 0; i < 2; i++) {
            acc[i][0] = bib.x; acc[i][1] = bib.y; acc[i][2] = bib.z; acc[i][3] = bib.w;
        }
    }
    #pragma unroll 8
    for (int k = 0; k < DIM; k++) {
        float4 b = *(const float4*)&sW[k * DIM + c0];
        float a0 = sT[r0 + 0][k], a1 = sT[r0 + 1][k];
        acc[0][0] = fmaf(a0, b.x, acc[0][0]); acc[0][1] = fmaf(a0, b.y, acc[0][1]);
        acc[0][2] = fmaf(a0, b.z, acc[0][2]); acc[0][3] = fmaf(a0, b.w, acc[0][3]);
        acc[1][0] = fmaf(a1, b.x, acc[1][0]); acc[1][1] = fmaf(a1, b.y, acc[1][1]);
        acc[1][2] = fmaf(a1, b.z, acc[1][2]); acc[1][3] = fmaf(a1, b.w, acc[1][3]);
    }
    __syncthreads();  // all GEMM2 reads of sT done (sT reused for pool walk)

    // relu; store bf16 (non-pool layers) or stage into sT (pool layer);
    // per-thread BN partials (valid rows only)
    float s[4] = {0.f, 0.f, 0.f, 0.f}, q[4] = {0.f, 0.f, 0.f, 0.f};
    #pragma unroll
    for (int i = 0; i < 2; i++) {
        int r = rbase + r0 + i;
        float4 o;
        o.x = fmaxf(acc[i][0], 0.f); o.y = fmaxf(acc[i][1], 0.f);
        o.z = fmaxf(acc[i][2], 0.f); o.w = fmaxf(acc[i][3], 0.f);
        if (r < N) {
            if (dopool) {
                *(float4*)&sT[r0 + i][c0] = o;
            } else {
                ushort4 ub;
                ub.x = f2bf(o.x); ub.y = f2bf(o.y); ub.z = f2bf(o.z); ub.w = f2bf(o.w);
                *(ushort4*)&hout[(size_t)r * DIM + c0] = ub;
            }
            s[0] += o.x; q[0] += o.x * o.x;
            s[1] += o.y; q[1] += o.y * o.y;
            s[2] += o.z; q[2] += o.z * o.z;
            s[3] += o.w; q[3] += o.w * o.w;
        }
    }
    // reduce over the row-groups within each wave: lanes +16, +32
    #pragma unroll
    for (int j = 0; j < 4; j++) {
        s[j] += __shfl_xor(s[j], 16); s[j] += __shfl_xor(s[j], 32);
        q[j] += __shfl_xor(q[j], 16); q[j] += __shfl_xor(q[j], 32);
    }
    if (lane < 16) {
        #pragma unroll
        for (int j = 0; j < 4; j++) {
            sred[wave][lane][j] = s[j];
            sred[wave][lane][4 + j] = q[j];
        }
    }
    __syncthreads();
    if (tid < DIM) {
        int txx = tid >> 2, j = tid & 3;
        float as = 0.f, aq = 0.f;
        #pragma unroll
        for (int w = 0; w < 8; w++) {
            as += sred[w][txx][j];
            aq += sred[w][txx][4 + j];
        }
        atomicAdd(&stats[tid], as);
        atomicAdd(&stats[DIM + tid], aq);
    }
    // pool walk: 64 channel-threads, serial over the block's 64 contiguous
    // rows, flush one atomicAdd per (graph, channel) run (~2 graphs/block)
    if (dopool && tid < DIM) {
        int ch = tid;
        float accp = 0.f;
        int g = sBatch[0];
        for (int rr = 0; rr < 64; rr++) {
            int gb = sBatch[rr];
            if (gb < 0) break;
            if (gb != g) {
                atomicAdd(&pool[(size_t)g * DIM + ch], accp);
                accp = 0.f; g = gb;
            }
            accp += sT[rr][ch];
        }
        atomicAdd(&pool[(size_t)g * DIM + ch], accp);
    }
}

// finalize: out[g] = sc * pool[g] + cnt_g * sh (BN3 affine folded through the
// linear pool). cnt_g via binary search (batch sorted); no h reads. One wave
// per graph.
__global__ void gin_finish(const float* __restrict__ pool, const int* __restrict__ batch,
                           const float* __restrict__ stats, const float* __restrict__ gamma,
                           const float* __restrict__ beta, float invN,
                           void* __restrict__ out, int N, int G,
                           const int* __restrict__ flag) {
    int gw = (blockIdx.x * blockDim.x + threadIdx.x) >> 6;
    int lane = threadIdx.x & 63;
    if (gw >= G) return;
    float m = stats[lane] * invN;
    float var = stats[DIM + lane] * invN - m * m;
    float sc = gamma[lane] * rsqrtf(var + BN_EPS);
    float sh = beta[lane] - sc * m;
    int lo = 0, hi = N;
    while (lo < hi) { int mid = (lo + hi) >> 1; if (batch[mid] < gw) lo = mid + 1; else hi = mid; }
    int s0 = lo;
    hi = N;
    while (lo < hi) { int mid = (lo + hi) >> 1; if (batch[mid] < gw + 1) lo = mid + 1; else hi = mid; }
    int cnt = lo - s0;
    float v = sc * pool[(size_t)gw * DIM + lane] + (float)cnt * sh;
    int f = flag[0];
    if (f) ((bf16*)out)[gw * DIM + lane] = __float2bfloat16(v);
    else   ((float*)out)[gw * DIM + lane] = v;
}

extern "C" void kernel_launch(void* const* d_in, const int* in_sizes, int n_in,
                              void* d_out, int out_size, void* d_ws, size_t ws_size,
                              hipStream_t stream) {
    (void)hipGetLastError();  // clear any stale error

    const int N = in_sizes[0] / DIM;   // F_IN == DIM == 64
    const int E = in_sizes[1] / 2;
    const int G = out_size / DIM;
    const size_t ND = (size_t)N * DIM;

    const void* x     = d_in[0];
    const int*  ei    = (const int*)d_in[1];
    const int*  srcp  = ei;
    const int*  dstp  = ei + E;
    const int*  batch = (const int*)d_in[2];

    // bucket shift: start at 8 (250-B mscatter runs); NBUCK <= 2048, W <= MAXW;
    // packed ebuf needs (src << SHIFT) to fit 32 bits.
    int SHIFT = 8;
    while ((((N - 1) >> SHIFT) + 1) > 2048) SHIFT++;
    const int NBUCK = ((N - 1) >> SHIFT) + 1;   // N=100k -> 391
    const int packed_ok = ((unsigned long long)(N - 1) << SHIFT) <= 0xFFFFFFFFull;

    // workspace layout (4-B units from d_ws)
    int*   flag   = (int*)d_ws;                  // [64]
    float* P      = (float*)d_ws + 64;           // [25600] staged f32 params
    int*   bcnt   = (int*)(P + 25600);           // [2048] counts -> bases
    int*   bcur   = bcnt + 2048;                 // [2048] reservation cursors
    float* stats  = (float*)(bcur + 2048);       // [384] = 3 layers x 128
    float* pool   = stats + 384;                 // [G*64] f32 graph sums
    int*   rowptr = (int*)(pool + (size_t)G * DIM);  // [N+1]
    int*   adj    = rowptr + (N + 1);            // [E]
    size_t ha4    = ((size_t)(adj - (int*)d_ws) + (size_t)E + 3) & ~(size_t)3;
    u16*   hA     = (u16*)((int*)d_ws + ha4);    // [ND] bf16 (16-B aligned)
    u16*   hB     = hA + ND;                     // [ND] bf16
    u32*   ebuf   = (u32*)hA;                    // [E] aliases h region (CSR build
                                                 // runs BEFORE x-convert)
    size_t need   = (char*)(hB + ND) - (char*)d_ws;
    if (ws_size < need || NBUCK > 2048 || (1 << SHIFT) > MAXW || !packed_ok) {
        hipMemsetAsync(d_out, 0x77, (size_t)out_size * 2, stream);  // ~5e33 marker
        return;
    }

    // param staging pack: per layer {wa, ba, wb, bb, gamma, beta}
    ParamPack pk;
    int off = 0;
    for (int l = 0; l < 3; l++) {
        for (int j = 0; j < 6; j++) {
            int idx = 3 + 6 * l + j;
            pk.p[6 * l + j]   = d_in[idx];
            pk.n[6 * l + j]   = in_sizes[idx];
            pk.off[6 * l + j] = off;
            off += in_sizes[idx];
        }
    }
    float* wa[3], *ba[3], *wb[3], *bb[3], *gm[3], *be[3];
    for (int l = 0; l < 3; l++) {
        float* base = P + l * 8448;
        wa[l] = base;        ba[l] = base + 4096;
        wb[l] = base + 4160; bb[l] = base + 8256;
        gm[l] = base + 8320; be[l] = base + 8384;
    }

    const int TB = 256;
    const int grid_nd4 = (int)((ND / 4 + TB - 1) / TB);
    const int grid_g   = (G * DIM + TB - 1) / TB;
    const int grid_mlp = (N + 63) / 64;
    const int grid_ms  = (E + MS_CHUNK - 1) / MS_CHUNK;
    const float invN   = 1.0f / (float)N;
    const int nzero    = 2048 + 2048 + 384 + G * DIM;   // bcnt|bcur|stats|pool

    // params staged + dtype detect fused (block 0 publishes flag)
    gin_cvt_params<<<18, 256, 0, stream>>>(pk, P, (const unsigned short*)d_in[3],
                                           in_sizes[3], flag);

    // ---- CSR build (once; ebuf aliases h region, so build before x-convert) ----
    gin_zero<<<(nzero + TB - 1) / TB, TB, 0, stream>>>((float*)bcnt, nzero);
    gin_bhist<<<256, 256, 0, stream>>>(dstp, bcnt, E, SHIFT, NBUCK);
    gin_scan2<<<1, 256, 0, stream>>>(bcnt, NBUCK);                     // -> excl. bases
    gin_mscatter<<<grid_ms, 512, 0, stream>>>(srcp, dstp, bcnt, bcur, ebuf, E, SHIFT, NBUCK);
    gin_bfill<<<NBUCK, 256, 0, stream>>>(ebuf, bcnt, rowptr, adj, E, N, SHIFT, NBUCK);

    // x -> bf16 h (no-op when input already bf16; L1 then reads x directly)
    GINEncoder_16114717295311_kernel<<<grid_nd4, TB, 0, stream>>>(x, hA, (int)(ND / 4), flag);

    // L1: x/hA -> hB (identity affine), L2: hB -> hA, L3: hA -> pool (no hout)
    gin_gmlp<<<grid_mlp, 512, 0, stream>>>(hA, hB, x, flag, rowptr, adj,
                                           nullptr, nullptr, nullptr,
                                           wa[0], ba[0], wb[0], bb[0],
                                           stats + 0, nullptr, nullptr, N, invN);
    gin_gmlp<<<grid_mlp, 512, 0, stream>>>(hB, hA, nullptr, flag, rowptr, adj,
                                           stats + 0, gm[0], be[0],
                                           wa[1], ba[1], wb[1], bb[1],
                                           stats + 128, nullptr, nullptr, N, invN);
    gin_gmlp<<<grid_mlp, 512, 0, stream>>>(hA, hB, nullptr, flag, rowptr, adj,
                                           stats + 128, gm[1], be[1],
                                           wa[2], ba[2], wb[2], bb[2],
                                           stats + 256, pool, batch, N, invN);

    gin_finish<<<grid_g, TB, 0, stream>>>(pool, batch, stats + 256, gm[2], be[2], invN,
                                          d_out, N, G, flag);

    // "some launch failed" marker: err prints ~1.7e38 (bf16) / 3.4e38 (f32)
    hipError_t e = hipGetLastError();
    if (e != hipSuccess) {
        hipMemsetAsync(d_out, 0x7F, (size_t)out_size * 2, stream);
    }
}